// Round 5
// baseline (505.575 us; speedup 1.0000x reference)
//
#include <hip/hip_runtime.h>
#include <hip/hip_bf16.h>
#include <cstdint>
#include <cstddef>

// Problem constants: data (4,8,4096,3) -> 32 batches x 4096 points
#define BT 32
#define N1 4096
#define S1 256
#define S2 128
#define KNB 32

typedef __attribute__((ext_vector_type(8))) short short8;   // 8 bf16 in 4 VGPRs
typedef __attribute__((ext_vector_type(4))) float f32x4;

__device__ __forceinline__ float sqdist(float ax, float ay, float az,
                                        float bx, float by, float bz) {
    // exact replication of sum((a-b)**2, axis=-1): mul then left-to-right add, NO fma
    float dx = __fsub_rn(ax, bx), dy = __fsub_rn(ay, by), dz = __fsub_rn(az, bz);
    return __fadd_rn(__fadd_rn(__fmul_rn(dx, dx), __fmul_rn(dy, dy)), __fmul_rn(dz, dz));
}

// bf16 round-to-nearest-even (values here are finite)
__device__ __forceinline__ unsigned short f2bf(float f) {
    unsigned u = __float_as_uint(f);
    return (unsigned short)((u + 0x7FFFu + ((u >> 16) & 1u)) >> 16);
}
__device__ __forceinline__ float bf2f(unsigned short h) {
    return __uint_as_float(((unsigned)h) << 16);
}

// pack (value, index) for argmax-with-first-index-tie-break: distances >= 0 so float
// bits are monotonic as uint; on equal value, larger ~idx == smaller idx wins.
__device__ __forceinline__ unsigned long long packvi(float v, int idx) {
    return ((unsigned long long)__float_as_uint(v) << 32) | (unsigned)(~idx);
}

// DPP row-rotate max for u64 (rotate within 16-lane rows; commutative reduce)
template <int CTRL>
__device__ __forceinline__ unsigned long long dppmax(unsigned long long v) {
    int lo = (int)(unsigned)(v & 0xFFFFFFFFull);
    int hi = (int)(unsigned)(v >> 32);
    int lo2 = __builtin_amdgcn_update_dpp(0, lo, CTRL, 0xF, 0xF, false);
    int hi2 = __builtin_amdgcn_update_dpp(0, hi, CTRL, 0xF, 0xF, false);
    unsigned long long o = ((unsigned long long)(unsigned)hi2 << 32) | (unsigned)lo2;
    return o > v ? o : v;
}
#define ROR1 0x121
#define ROR2 0x122
#define ROR4 0x124
#define ROR8 0x128

// wave-level ball query: scans X[0..n), radius^2 r2, writes KNB indices to gl[].
// EXACT semantics of the standalone kernels (ascending-index fill, first-hit pad).
// R17 note: with this data distribution the early-exit never fires (hits << 32), so
// every wave does the full scan — which is why fusing it under MFMA kernels is free.
__device__ __forceinline__ void ballq_wave(const float* __restrict__ X, int n,
                                           float cx, float cy, float cz, float r2,
                                           int lane, int* __restrict__ gl) {
    int cnt = 0, first = 0;
    bool found = false;
    for (int j0 = 0; j0 < n && cnt < KNB; j0 += 64) {
        int j = j0 + lane;
        float d2 = sqdist(cx, cy, cz, X[j * 3 + 0], X[j * 3 + 1], X[j * 3 + 2]);
        bool hit = d2 < r2;
        unsigned long long mask = __ballot(hit);
        if (!found && mask) { first = j0 + __builtin_ctzll(mask); found = true; }
        if (hit) {
            int pos = cnt + __popcll(mask & ((1ull << lane) - 1ull));
            if (pos < KNB) gl[pos] = j;
        }
        cnt += __popcll(mask);
    }
    if (cnt < KNB) {
        int pad = found ? first : 0;
        if (lane >= cnt && lane < KNB) gl[lane] = pad;
    }
}

// ---------------- FPS module 1 + wconv PACKED into one launch (R15, kept) -----------
// fps1: blocks 0..31 (one per batch, EXACT byte-for-byte R8/R9/R11-proven 153us code).
// wconv: blocks 32..3247 (~5us + launch gap hidden under fps1's 153us serial chain).
// FPS DO-NOT-TOUCH ledger (all measured equal or worse): 512-thr (per-CU issue-bound),
// payload-DPP reduce, coord-prefetch, single-slot LDS atomicMax (R13: +65us, DS
// serializes same-address RMW), f32x2 pk math (R14: +49us, v_pk_*_f32 has NO
// issue-rate gain on CDNA4), tree argmax (R14, part of +49us).
// fps1 per-iter critical path ~1440cyc = compute ~400 + sync chain ~1000 — structural
// for 4-wave cross-wave argmax; accepted.
//
//  w11b@0      64x64   | w12b@4096  128x64 | w20p@12288 128x192 (PERM: feat-first)
//  w21b@36864  128x128 | w22b@53248 256x128| w30p@86016 256x320 (PERM: feat-first)
//  w31b@167936 512x256 | w32b@299008 1024x512  total 823296
__global__ __launch_bounds__(256) void fps1_wconv_kernel(
    const float* __restrict__ xyz, float* __restrict__ nxz,
    const float* __restrict__ w11, const float* __restrict__ w12,
    const float* __restrict__ w20, const float* __restrict__ w21,
    const float* __restrict__ w22, const float* __restrict__ w30,
    const float* __restrict__ w31, const float* __restrict__ w32,
    unsigned short* __restrict__ wb) {
    if (blockIdx.x < 32) {
        // ================= fps1 (EXACT proven code, b = blockIdx.x) =================
        const int b = blockIdx.x, tid = threadIdx.x;
        const int lane = tid & 63, wv = tid >> 6;      // 4 waves
        const float* X = xyz + (size_t)b * (N1 * 3);
        __shared__ float4 s4[N1];                      // 64 KB
        __shared__ unsigned long long slots[2][16];
        __shared__ float hist[S1 * 3];
        float px[16], py[16], pz[16], md[16];
        int bidx[16];
#pragma unroll
        for (int j = 0; j < 16; ++j) {
            int i = tid + 256 * j;
            float x = X[i * 3 + 0], y = X[i * 3 + 1], z = X[i * 3 + 2];
            s4[i] = make_float4(x, y, z, 0.f);
            px[j] = x; py[j] = y; pz[j] = z;
            md[j] = 1e10f;
            bidx[j] = i;
        }
        if (tid == 0) { hist[0] = X[0]; hist[1] = X[1]; hist[2] = X[2]; }
        __syncthreads();
        float4 c0 = s4[0];
        float lx = c0.x, ly = c0.y, lz = c0.z;
        for (int t = 1; t < S1; ++t) {
            float bv = -1.0f; int bi = 0;
#pragma unroll
            for (int j = 0; j < 16; ++j) {
                float d = sqdist(px[j], py[j], pz[j], lx, ly, lz);
                float m = fminf(md[j], d);
                md[j] = m;
                if (m > bv) { bv = m; bi = bidx[j]; }   // ascending flat idx: first max kept
            }
            unsigned long long best = packvi(bv, bi);
            best = dppmax<ROR1>(best);
            best = dppmax<ROR2>(best);
            best = dppmax<ROR4>(best);
            best = dppmax<ROR8>(best);                  // row (16-lane) max
            if ((lane & 15) == 0) slots[t & 1][wv * 4 + (lane >> 4)] = best;
            __syncthreads();
            unsigned long long w = slots[t & 1][lane & 15];
            w = dppmax<ROR1>(w);
            w = dppmax<ROR2>(w);
            w = dppmax<ROR4>(w);
            w = dppmax<ROR8>(w);
            int vi = (int)(~(unsigned)w);
            float4 c = s4[vi];
            lx = c.x; ly = c.y; lz = c.z;
            if (tid == 0) { hist[t * 3 + 0] = lx; hist[t * 3 + 1] = ly; hist[t * 3 + 2] = lz; }
        }
        __syncthreads();
        for (int u = tid; u < S1 * 3; u += 256) nxz[(size_t)b * S1 * 3 + u] = hist[u];
    } else {
        // ================= wconv (blocks 32..3247; u covers 0..823295) ==============
        int u = (blockIdx.x - 32) * 256 + threadIdx.x;
        if (u >= 823296) return;
        const float* src; int base, Kp, Ko; int perm = 0;   // perm: feature-count, feat-first
        if      (u < 4096)   { src = w11; base = 0;      Kp = 64;  Ko = 64;  }
        else if (u < 12288)  { src = w12; base = 4096;   Kp = 64;  Ko = 64;  }
        else if (u < 36864)  { src = w20; base = 12288;  Kp = 192; Ko = 131; perm = 128; }
        else if (u < 53248)  { src = w21; base = 36864;  Kp = 128; Ko = 128; }
        else if (u < 86016)  { src = w22; base = 53248;  Kp = 128; Ko = 128; }
        else if (u < 167936) { src = w30; base = 86016;  Kp = 320; Ko = 259; perm = 256; }
        else if (u < 299008) { src = w31; base = 167936; Kp = 256; Ko = 256; }
        else                 { src = w32; base = 299008; Kp = 512; Ko = 512; }
        int local = u - base;
        int n = local / Kp, k = local - n * Kp;
        float v;
        if (perm) {
            int ksrc = (k < perm) ? (k + 3) : ((k < perm + 3) ? (k - perm) : -1);
            v = (ksrc >= 0) ? src[(size_t)n * Ko + ksrc] : 0.f;
        } else {
            v = (k < Ko) ? src[(size_t)n * Ko + k] : 0.f;
        }
        wb[u] = f2bf(v);
    }
}

// ---------------- L2: fps2 + m1(with INLINE ballq1) PACKED (R17) ---------------------
// fps2 (blocks 0..31, first): 26us serial chain, hidden under m1.
// m1 (blocks 32..2079): each block needs neighbor lists for exactly 4 centers
// ((m0>>5)..+3) — one per wave. R17: each wave runs the ball-query scan itself
// (ballq1's early-exit never fires on this data, so it was a full 64-iter scan in a
// dedicated ~15-25us launch; inlined here it overlaps with MFMA/LDS phases of
// co-resident blocks and the launch disappears).
__global__ __launch_bounds__(256) void m1bq_fps2_kernel(
    const float* __restrict__ xyz, const float* __restrict__ nxz,
    const float* __restrict__ w10, const float* __restrict__ b10,
    const unsigned short* __restrict__ w11b, const float* __restrict__ b11,
    const unsigned short* __restrict__ w12b, const float* __restrict__ b12,
    unsigned short* __restrict__ f1,
    float* __restrict__ nxz2) {
    if (blockIdx.x < 32) {
        // ================= fps2 (one wave per batch; threads 64..255 exit) ==========
        if (threadIdx.x >= 64) return;
        const int b = blockIdx.x, lane = threadIdx.x;
        const float* X = nxz + (size_t)b * (S1 * 3);
        __shared__ float4 s4f[S1];
        float px[4], py[4], pz[4], md[4];
        int bidx[4];
#pragma unroll
        for (int j = 0; j < 4; ++j) {
            int i = lane + 64 * j;
            float x = X[i * 3 + 0], y = X[i * 3 + 1], z = X[i * 3 + 2];
            s4f[i] = make_float4(x, y, z, 0.f);
            px[j] = x; py[j] = y; pz[j] = z;
            md[j] = 1e10f;
            bidx[j] = i;
        }
        if (lane == 0) {
            nxz2[(size_t)b * S2 * 3 + 0] = X[0];
            nxz2[(size_t)b * S2 * 3 + 1] = X[1];
            nxz2[(size_t)b * S2 * 3 + 2] = X[2];
        }
        // single wave: LDS writes above are wave-synchronous
        float4 cc = s4f[0];
        float lx = cc.x, ly = cc.y, lz = cc.z;
        for (int t = 1; t < S2; ++t) {
            float bv = -1.0f; int bi = 0;
#pragma unroll
            for (int j = 0; j < 4; ++j) {
                float d = sqdist(px[j], py[j], pz[j], lx, ly, lz);
                float m = fminf(md[j], d);
                md[j] = m;
                if (m > bv) { bv = m; bi = bidx[j]; }
            }
            unsigned long long best = packvi(bv, bi);
            best = dppmax<ROR1>(best);
            best = dppmax<ROR2>(best);
            best = dppmax<ROR4>(best);
            best = dppmax<ROR8>(best);
            { unsigned long long o = __shfl_xor(best, 16); best = o > best ? o : best; }
            { unsigned long long o = __shfl_xor(best, 32); best = o > best ? o : best; }
            int vi = (int)(~(unsigned)best);
            float4 c = s4f[vi];
            lx = c.x; ly = c.y; lz = c.z;
            if (lane == 0) {
                float* dst = nxz2 + ((size_t)b * S2 + t) * 3;
                dst[0] = lx; dst[1] = ly; dst[2] = lz;
            }
        }
        return;
    }
    // ================= m1 (blocks 32..2079) =========================================
    constexpr int AP = 72;
    __shared__ __align__(16) unsigned short As[128 * AP];
    __shared__ __align__(16) unsigned short Hs[128 * AP];
    __shared__ __align__(16) unsigned short Bs[192 * AP];   // w11 (64 rows) + w12 (128 rows)
    __shared__ float sxyz[128 * 3];
    __shared__ int gl[4][KNB];
    const int t = threadIdx.x;
    const int lane = t & 63, w = t >> 6;
    const int r16 = lane & 15, q = lane >> 4;
    const int m0 = (blockIdx.x - 32) * 128;

    // stage w11 (rows 0..63) and w12 (rows 64..191) in one pass (independent of ballq)
    for (int c = t; c < 192 * 8; c += 256) {
        int row = c >> 3, ch = c & 7;
        const unsigned short* src = (row < 64) ? &w11b[row * 64 + ch * 8]
                                               : &w12b[(row - 64) * 64 + ch * 8];
        *(short8*)&Bs[row * AP + ch * 8] = *(const short8*)src;
    }
    // ---- inline ballq1: wave w computes center (m0>>5)+w's 32-neighbor list ----
    {
        const int cs = (m0 >> 5) + w;          // global center id [0,8192)
        const int bb = cs >> 8;
        const float* Cc = nxz + (size_t)cs * 3;
        ballq_wave(xyz + (size_t)bb * (N1 * 3), N1,
                   Cc[0], Cc[1], Cc[2], (float)(0.2 * 0.2), lane, gl[w]);
    }
    __syncthreads();                            // gl ready for cross-wave gather
    if (t < 128) {
        int row = m0 + t, bs = row >> 5, b = bs >> 8, j = gl[t >> 5][t & 31];
        const float* P = xyz + ((size_t)b * N1 + j) * 3;
        const float* Cc = nxz + (size_t)bs * 3;
        sxyz[t * 3 + 0] = P[0] - Cc[0];
        sxyz[t * 3 + 1] = P[1] - Cc[1];
        sxyz[t * 3 + 2] = P[2] - Cc[2];
    }
    __syncthreads();
    {
        const int r = t >> 1, half = (t & 1) * 32;
        const float x = sxyz[r * 3 + 0], y = sxyz[r * 3 + 1], z = sxyz[r * 3 + 2];
        unsigned short tmp[32];
#pragma unroll
        for (int o = 0; o < 32; ++o) {
            int oo = half + o;
            float acc = b10[oo];
            acc = fmaf(x, w10[oo * 3 + 0], acc);
            acc = fmaf(y, w10[oo * 3 + 1], acc);
            acc = fmaf(z, w10[oo * 3 + 2], acc);
            tmp[o] = f2bf(fmaxf(acc, 0.f));
        }
#pragma unroll
        for (int c2 = 0; c2 < 4; ++c2)
            *(short8*)&As[r * AP + half + c2 * 8] = *(short8*)&tmp[c2 * 8];
    }
    __syncthreads();
    {
        f32x4 acc[2][4];
#pragma unroll
        for (int i = 0; i < 2; ++i)
#pragma unroll
            for (int j = 0; j < 4; ++j) acc[i][j] = (f32x4){0.f, 0.f, 0.f, 0.f};
#pragma unroll
        for (int kk = 0; kk < 64; kk += 32) {
            short8 a0 = *(const short8*)&As[(w * 32 + r16) * AP + kk + q * 8];
            short8 a1 = *(const short8*)&As[(w * 32 + 16 + r16) * AP + kk + q * 8];
#pragma unroll
            for (int j = 0; j < 4; ++j) {
                short8 bf = *(const short8*)&Bs[(j * 16 + r16) * AP + kk + q * 8];
                acc[0][j] = __builtin_amdgcn_mfma_f32_16x16x32_bf16(a0, bf, acc[0][j], 0, 0, 0);
                acc[1][j] = __builtin_amdgcn_mfma_f32_16x16x32_bf16(a1, bf, acc[1][j], 0, 0, 0);
            }
        }
#pragma unroll
        for (int i = 0; i < 2; ++i)
#pragma unroll
            for (int j = 0; j < 4; ++j) {
                int col = j * 16 + r16;
                float bv = b11[col];
#pragma unroll
                for (int r = 0; r < 4; ++r) {
                    int row = w * 32 + i * 16 + q * 4 + r;
                    Hs[row * AP + col] = f2bf(fmaxf(acc[i][j][r] + bv, 0.f));
                }
            }
    }
    __syncthreads();   // Hs fully written; Bs rows 64.. already hold w12
    {
        f32x4 acc[2][8];
#pragma unroll
        for (int i = 0; i < 2; ++i)
#pragma unroll
            for (int j = 0; j < 8; ++j) acc[i][j] = (f32x4){0.f, 0.f, 0.f, 0.f};
#pragma unroll
        for (int kk = 0; kk < 64; kk += 32) {
            short8 a0 = *(const short8*)&Hs[(w * 32 + r16) * AP + kk + q * 8];
            short8 a1 = *(const short8*)&Hs[(w * 32 + 16 + r16) * AP + kk + q * 8];
#pragma unroll
            for (int j = 0; j < 8; ++j) {
                short8 bf = *(const short8*)&Bs[(64 + j * 16 + r16) * AP + kk + q * 8];
                acc[0][j] = __builtin_amdgcn_mfma_f32_16x16x32_bf16(a0, bf, acc[0][j], 0, 0, 0);
                acc[1][j] = __builtin_amdgcn_mfma_f32_16x16x32_bf16(a1, bf, acc[1][j], 0, 0, 0);
            }
        }
#pragma unroll
        for (int j = 0; j < 8; ++j) {
            int col = j * 16 + r16;
            float bv = b12[col];
            float mv = 0.f;
#pragma unroll
            for (int i = 0; i < 2; ++i)
#pragma unroll
                for (int r = 0; r < 4; ++r)
                    mv = fmaxf(mv, acc[i][j][r] + bv);
            mv = fmaxf(mv, __shfl_xor(mv, 16));
            mv = fmaxf(mv, __shfl_xor(mv, 32));
            if (q == 0)
                f1[(size_t)((m0 >> 5) + w) * 128 + col] = f2bf(mv);
        }
    }
}

// ---------------- L3: Module 2 fully fused + INLINE ballq2 (R17) ---------------------
// Each block needs g2 for exactly 4 centers ((m0>>5)..+3); each wave computes its own
// (4-iteration scan over S1=256 pts, L2-hot). Removes the ballq2 launch + g2 roundtrip.
// R12 core kept: w21 staged into R1 in ONE pass.
__global__ __launch_bounds__(256) void m2bq_kernel(
    const float* __restrict__ xyz1, const float* __restrict__ nxz2,
    const unsigned short* __restrict__ f1,
    const unsigned short* __restrict__ w20p, const float* __restrict__ b20,
    const unsigned short* __restrict__ w21b, const float* __restrict__ b21,
    const unsigned short* __restrict__ w22b, const float* __restrict__ b22,
    unsigned short* __restrict__ f2) {
    constexpr int AP = 72, HP = 136;
    __shared__ __align__(16) unsigned short smem[36864];   // 72 KB
    unsigned short* R1 = smem;
    unsigned short* R2 = smem + 18432;
    unsigned short* As = R1;
    unsigned short* Bs = R1 + 9216;
    unsigned short* W21 = R1;            // full w21, stride HP (17408 shorts)
    unsigned short* H1 = R2;
    unsigned short* H2 = R1;
    unsigned short* Bs2 = R2;
    __shared__ int ribase[128];
    __shared__ unsigned short sxb[128 * 3];
    __shared__ int gl2[4][KNB];
    const int t = threadIdx.x;
    const int lane = t & 63, w = t >> 6;
    const int r16 = lane & 15, q = lane >> 4;
    const int m0 = blockIdx.x * 128;

    // ---- inline ballq2: wave w computes center (m0>>5)+w's 32-neighbor list ----
    {
        const int cs = (m0 >> 5) + w;          // global center id [0,4096)
        const int bb = cs >> 7;
        const float* Cc = nxz2 + (size_t)cs * 3;
        ballq_wave(xyz1 + (size_t)bb * (S1 * 3), S1,
                   Cc[0], Cc[1], Cc[2], (float)(0.4 * 0.4), lane, gl2[w]);
    }
    __syncthreads();                            // gl2 ready for cross-wave gather
    if (t < 128) {
        int row = m0 + t, bs = row >> 5, b = bs >> 7, j = gl2[t >> 5][t & 31];
        ribase[t] = (b * 256 + j) * 128;
        const float* P = xyz1 + ((size_t)b * S1 + j) * 3;
        const float* Cc = nxz2 + (size_t)bs * 3;
        sxb[t * 3 + 0] = f2bf(P[0] - Cc[0]);
        sxb[t * 3 + 1] = f2bf(P[1] - Cc[1]);
        sxb[t * 3 + 2] = f2bf(P[2] - Cc[2]);
    }
    __syncthreads();

    // ---- L0: K=192 (3 tiles), N=128 ----
    f32x4 acc[2][8];
#pragma unroll
    for (int i = 0; i < 2; ++i)
#pragma unroll
        for (int j = 0; j < 8; ++j) acc[i][j] = (f32x4){0.f, 0.f, 0.f, 0.f};
    for (int kt = 0; kt < 3; ++kt) {
        const int k0 = kt * 64;
        if (kt < 2) {
            for (int c = t; c < 128 * 8; c += 256) {
                int row = c >> 3, ch = c & 7;
                *(short8*)&As[row * AP + ch * 8] =
                    *(const short8*)&f1[(size_t)ribase[row] + k0 + ch * 8];
            }
        } else {
            for (int c = t; c < 128 * 8; c += 256) {
                int row = c >> 3, ch = c & 7;
                short8 v = (short8){0, 0, 0, 0, 0, 0, 0, 0};
                if (ch == 0) {
                    v[0] = (short)sxb[row * 3 + 0];
                    v[1] = (short)sxb[row * 3 + 1];
                    v[2] = (short)sxb[row * 3 + 2];
                }
                *(short8*)&As[row * AP + ch * 8] = v;
            }
        }
        for (int c = t; c < 128 * 8; c += 256) {
            int row = c >> 3, ch = c & 7;
            *(short8*)&Bs[row * AP + ch * 8] =
                *(const short8*)&w20p[(size_t)row * 192 + k0 + ch * 8];
        }
        __syncthreads();
#pragma unroll
        for (int kk = 0; kk < 64; kk += 32) {
            short8 a0 = *(const short8*)&As[(w * 32 + r16) * AP + kk + q * 8];
            short8 a1 = *(const short8*)&As[(w * 32 + 16 + r16) * AP + kk + q * 8];
#pragma unroll
            for (int j = 0; j < 8; ++j) {
                short8 bf = *(const short8*)&Bs[(j * 16 + r16) * AP + kk + q * 8];
                acc[0][j] = __builtin_amdgcn_mfma_f32_16x16x32_bf16(a0, bf, acc[0][j], 0, 0, 0);
                acc[1][j] = __builtin_amdgcn_mfma_f32_16x16x32_bf16(a1, bf, acc[1][j], 0, 0, 0);
            }
        }
        __syncthreads();
    }
#pragma unroll
    for (int i = 0; i < 2; ++i)
#pragma unroll
        for (int j = 0; j < 8; ++j) {
            int col = j * 16 + r16;
            float bv = b20[col];
#pragma unroll
            for (int r = 0; r < 4; ++r) {
                int row = w * 32 + i * 16 + q * 4 + r;
                H1[row * HP + col] = f2bf(fmaxf(acc[i][j][r] + bv, 0.f));
            }
        }
    // ---- L1: K=128, N=128; stage FULL w21 into R1 (As/Bs dead), single barrier ----
    __syncthreads();
    for (int c = t; c < 128 * 16; c += 256) {
        int row = c >> 4, ch = c & 15;
        *(short8*)&W21[row * HP + ch * 8] =
            *(const short8*)&w21b[(size_t)row * 128 + ch * 8];
    }
    __syncthreads();
#pragma unroll
    for (int i = 0; i < 2; ++i)
#pragma unroll
        for (int j = 0; j < 8; ++j) acc[i][j] = (f32x4){0.f, 0.f, 0.f, 0.f};
#pragma unroll
    for (int kk = 0; kk < 128; kk += 32) {
        short8 a0 = *(const short8*)&H1[(w * 32 + r16) * HP + kk + q * 8];
        short8 a1 = *(const short8*)&H1[(w * 32 + 16 + r16) * HP + kk + q * 8];
#pragma unroll
        for (int j = 0; j < 8; ++j) {
            short8 bf = *(const short8*)&W21[(j * 16 + r16) * HP + kk + q * 8];
            acc[0][j] = __builtin_amdgcn_mfma_f32_16x16x32_bf16(a0, bf, acc[0][j], 0, 0, 0);
            acc[1][j] = __builtin_amdgcn_mfma_f32_16x16x32_bf16(a1, bf, acc[1][j], 0, 0, 0);
        }
    }
    __syncthreads();   // all waves done reading W21 (R1); H2 overwrites R1
#pragma unroll
    for (int i = 0; i < 2; ++i)
#pragma unroll
        for (int j = 0; j < 8; ++j) {
            int col = j * 16 + r16;
            float bv = b21[col];
#pragma unroll
            for (int r = 0; r < 4; ++r) {
                int row = w * 32 + i * 16 + q * 4 + r;
                H2[row * HP + col] = f2bf(fmaxf(acc[i][j][r] + bv, 0.f));
            }
        }
    __syncthreads();

    // ---- L2: K=128 (2 tiles), N=256 + pool ----
    f32x4 acc2[2][16];
#pragma unroll
    for (int i = 0; i < 2; ++i)
#pragma unroll
        for (int j = 0; j < 16; ++j) acc2[i][j] = (f32x4){0.f, 0.f, 0.f, 0.f};
    for (int kt = 0; kt < 2; ++kt) {
        const int k0 = kt * 64;
        for (int c = t; c < 256 * 8; c += 256) {
            int row = c >> 3, ch = c & 7;
            *(short8*)&Bs2[row * AP + ch * 8] =
                *(const short8*)&w22b[(size_t)row * 128 + k0 + ch * 8];
        }
        __syncthreads();
#pragma unroll
        for (int kk = 0; kk < 64; kk += 32) {
            short8 a0 = *(const short8*)&H2[(w * 32 + r16) * HP + k0 + kk + q * 8];
            short8 a1 = *(const short8*)&H2[(w * 32 + 16 + r16) * HP + k0 + kk + q * 8];
#pragma unroll
            for (int j = 0; j < 16; ++j) {
                short8 bf = *(const short8*)&Bs2[(j * 16 + r16) * AP + kk + q * 8];
                acc2[0][j] = __builtin_amdgcn_mfma_f32_16x16x32_bf16(a0, bf, acc2[0][j], 0, 0, 0);
                acc2[1][j] = __builtin_amdgcn_mfma_f32_16x16x32_bf16(a1, bf, acc2[1][j], 0, 0, 0);
            }
        }
        __syncthreads();
    }
#pragma unroll
    for (int j = 0; j < 16; ++j) {
        int col = j * 16 + r16;
        float bv = b22[col];
        float mv = 0.f;
#pragma unroll
        for (int i = 0; i < 2; ++i)
#pragma unroll
            for (int r = 0; r < 4; ++r)
                mv = fmaxf(mv, acc2[i][j][r] + bv);
        mv = fmaxf(mv, __shfl_xor(mv, 16));
        mv = fmaxf(mv, __shfl_xor(mv, 32));
        if (q == 0)
            f2[(size_t)((m0 >> 5) + w) * 256 + col] = f2bf(mv);
    }
}

// ---------------- Module 3 layer 0 with fused concat (feat-first K=320) ---------------
__global__ __launch_bounds__(256) void l30_kernel(
    const float* __restrict__ nxz2, const unsigned short* __restrict__ f2,
    const unsigned short* __restrict__ w30p, const float* __restrict__ bias,
    unsigned short* __restrict__ C) {
    constexpr int AP = 72;
    __shared__ __align__(16) unsigned short As[128 * AP];
    __shared__ __align__(16) unsigned short Bs[128 * AP];
    const int t = threadIdx.x;
    const int lane = t & 63, w = t >> 6;
    const int r16 = lane & 15, q = lane >> 4;
    const int m0 = blockIdx.x * 128;
    const int n0 = blockIdx.y * 128;

    f32x4 acc[2][8];
#pragma unroll
    for (int i = 0; i < 2; ++i)
#pragma unroll
        for (int j = 0; j < 8; ++j) acc[i][j] = (f32x4){0.f, 0.f, 0.f, 0.f};

    for (int kt = 0; kt < 5; ++kt) {
        const int k0 = kt * 64;
        if (kt < 4) {
            for (int c = t; c < 128 * 8; c += 256) {
                int row = c >> 3, ch = c & 7;
                *(short8*)&As[row * AP + ch * 8] =
                    *(const short8*)&f2[(size_t)(m0 + row) * 256 + k0 + ch * 8];
            }
        } else {
            for (int c = t; c < 128 * 8; c += 256) {
                int row = c >> 3, ch = c & 7;
                short8 v = (short8){0, 0, 0, 0, 0, 0, 0, 0};
                if (ch == 0) {
                    const float* P = nxz2 + (size_t)(m0 + row) * 3;
                    v[0] = (short)f2bf(P[0]);
                    v[1] = (short)f2bf(P[1]);
                    v[2] = (short)f2bf(P[2]);
                }
                *(short8*)&As[row * AP + ch * 8] = v;
            }
        }
        for (int c = t; c < 128 * 8; c += 256) {
            int row = c >> 3, ch = c & 7;
            *(short8*)&Bs[row * AP + ch * 8] =
                *(const short8*)&w30p[(size_t)(n0 + row) * 320 + k0 + ch * 8];
        }
        __syncthreads();
#pragma unroll
        for (int kk = 0; kk < 64; kk += 32) {
            short8 a0 = *(const short8*)&As[(w * 32 + r16) * AP + kk + q * 8];
            short8 a1 = *(const short8*)&As[(w * 32 + 16 + r16) * AP + kk + q * 8];
#pragma unroll
            for (int j = 0; j < 8; ++j) {
                short8 bf = *(const short8*)&Bs[(j * 16 + r16) * AP + kk + q * 8];
                acc[0][j] = __builtin_amdgcn_mfma_f32_16x16x32_bf16(a0, bf, acc[0][j], 0, 0, 0);
                acc[1][j] = __builtin_amdgcn_mfma_f32_16x16x32_bf16(a1, bf, acc[1][j], 0, 0, 0);
            }
        }
        __syncthreads();
    }
#pragma unroll
    for (int i = 0; i < 2; ++i)
#pragma unroll
        for (int j = 0; j < 8; ++j) {
            int col = n0 + j * 16 + r16;
            float bv = bias[col];
#pragma unroll
            for (int r = 0; r < 4; ++r) {
                int row = m0 + w * 32 + i * 16 + q * 4 + r;
                C[(size_t)row * 256 + col] = f2bf(fmaxf(acc[i][j][r] + bv, 0.f));
            }
        }
}

// ---------------- bf16 MFMA GEMM (BM templated): C = relu(X*W^T + bias), BN=128 --------
template <int BM_>
__global__ __launch_bounds__(256) void mfma_gemm(const unsigned short* __restrict__ X,
                                                 const unsigned short* __restrict__ W,
                                                 const float* __restrict__ bias,
                                                 unsigned short* __restrict__ C,
                                                 int M, int N, int K) {
    constexpr int BK = 64, AP = BK + 8;
    constexpr int RW = BM_ / 64;         // M-frags per wave
    constexpr int WR = BM_ / 4;          // rows per wave
    __shared__ __align__(16) unsigned short As[BM_ * AP];
    __shared__ __align__(16) unsigned short Bs[128 * AP];
    const int t = threadIdx.x;
    const int lane = t & 63, w = t >> 6;
    const int m0 = blockIdx.x * BM_;
    const int n0 = blockIdx.y * 128;
    const int r16 = lane & 15, q = lane >> 4;

    f32x4 acc[RW][8];
#pragma unroll
    for (int i = 0; i < RW; ++i)
#pragma unroll
        for (int j = 0; j < 8; ++j) acc[i][j] = (f32x4){0.f, 0.f, 0.f, 0.f};

    for (int k0 = 0; k0 < K; k0 += BK) {
        for (int c = t; c < BM_ * 8; c += 256) {
            int row = c >> 3, ch = c & 7;
            *(short8*)&As[row * AP + ch * 8] =
                *(const short8*)&X[(size_t)(m0 + row) * K + k0 + ch * 8];
        }
        for (int c = t; c < 128 * 8; c += 256) {
            int row = c >> 3, ch = c & 7;
            *(short8*)&Bs[row * AP + ch * 8] =
                *(const short8*)&W[(size_t)(n0 + row) * K + k0 + ch * 8];
        }
        __syncthreads();
#pragma unroll
        for (int kk = 0; kk < BK; kk += 32) {
            short8 a[RW];
#pragma unroll
            for (int i = 0; i < RW; ++i)
                a[i] = *(const short8*)&As[(w * WR + i * 16 + r16) * AP + kk + q * 8];
#pragma unroll
            for (int j = 0; j < 8; ++j) {
                short8 bf = *(const short8*)&Bs[(j * 16 + r16) * AP + kk + q * 8];
#pragma unroll
                for (int i = 0; i < RW; ++i)
                    acc[i][j] = __builtin_amdgcn_mfma_f32_16x16x32_bf16(a[i], bf, acc[i][j], 0, 0, 0);
            }
        }
        __syncthreads();
    }
#pragma unroll
    for (int i = 0; i < RW; ++i)
#pragma unroll
        for (int j = 0; j < 8; ++j) {
            int col = n0 + j * 16 + r16;
            float bv = bias[col];
#pragma unroll
            for (int r = 0; r < 4; ++r) {
                int row = m0 + w * WR + i * 16 + q * 4 + r;
                C[(size_t)row * N + col] = f2bf(fmaxf(acc[i][j][r] + bv, 0.f));
            }
        }
}

// ---------------- Final GEMM (N=1024, K=512) + max over 128 rows -> fp32 out ----------
__global__ __launch_bounds__(256) void gemm_pool128(const unsigned short* __restrict__ X,
                                                    const unsigned short* __restrict__ W,
                                                    const float* __restrict__ bias,
                                                    float* __restrict__ out) {
    constexpr int BK = 64, AP = BK + 8, K = 512;
    __shared__ __align__(16) unsigned short As[128 * AP];
    __shared__ __align__(16) unsigned short Bs[128 * AP];
    __shared__ float pool[4][128];
    const int t = threadIdx.x;
    const int lane = t & 63, w = t >> 6;
    const int m0 = blockIdx.x * 128;
    const int n0 = blockIdx.y * 128;
    const int r16 = lane & 15, q = lane >> 4;

    f32x4 acc[2][8];
#pragma unroll
    for (int i = 0; i < 2; ++i)
#pragma unroll
        for (int j = 0; j < 8; ++j) acc[i][j] = (f32x4){0.f, 0.f, 0.f, 0.f};

    for (int k0 = 0; k0 < K; k0 += BK) {
        for (int c = t; c < 128 * 8; c += 256) {
            int row = c >> 3, ch = c & 7;
            *(short8*)&As[row * AP + ch * 8] =
                *(const short8*)&X[(size_t)(m0 + row) * K + k0 + ch * 8];
        }
        for (int c = t; c < 128 * 8; c += 256) {
            int row = c >> 3, ch = c & 7;
            *(short8*)&Bs[row * AP + ch * 8] =
                *(const short8*)&W[(size_t)(n0 + row) * K + k0 + ch * 8];
        }
        __syncthreads();
#pragma unroll
        for (int kk = 0; kk < BK; kk += 32) {
            short8 a0 = *(const short8*)&As[(w * 32 + r16) * AP + kk + q * 8];
            short8 a1 = *(const short8*)&As[(w * 32 + 16 + r16) * AP + kk + q * 8];
#pragma unroll
            for (int j = 0; j < 8; ++j) {
                short8 bf = *(const short8*)&Bs[(j * 16 + r16) * AP + kk + q * 8];
                acc[0][j] = __builtin_amdgcn_mfma_f32_16x16x32_bf16(a0, bf, acc[0][j], 0, 0, 0);
                acc[1][j] = __builtin_amdgcn_mfma_f32_16x16x32_bf16(a1, bf, acc[1][j], 0, 0, 0);
            }
        }
        __syncthreads();
    }
    // wave-level pool over its 32 rows (relu via 0-init), then cross-wave via LDS
#pragma unroll
    for (int j = 0; j < 8; ++j) {
        float bv = bias[n0 + j * 16 + r16];
        float mv = 0.f;
#pragma unroll
        for (int i = 0; i < 2; ++i)
#pragma unroll
            for (int r = 0; r < 4; ++r)
                mv = fmaxf(mv, acc[i][j][r] + bv);
        mv = fmaxf(mv, __shfl_xor(mv, 16));
        mv = fmaxf(mv, __shfl_xor(mv, 32));
        if (q == 0) pool[w][j * 16 + r16] = mv;
    }
    __syncthreads();
    if (t < 128) {
        float m = fmaxf(fmaxf(pool[0][t], pool[1][t]), fmaxf(pool[2][t], pool[3][t]));
        out[(size_t)blockIdx.x * 1024 + n0 + t] = m;
    }
}

extern "C" void kernel_launch(void* const* d_in, const int* in_sizes, int n_in,
                              void* d_out, int out_size, void* d_ws, size_t ws_size,
                              hipStream_t stream) {
    const float* data = (const float*)d_in[0];
    const float* w10 = (const float*)d_in[1];  const float* b10 = (const float*)d_in[2];
    const float* w11 = (const float*)d_in[3];  const float* b11 = (const float*)d_in[4];
    const float* w12 = (const float*)d_in[5];  const float* b12 = (const float*)d_in[6];
    const float* w20 = (const float*)d_in[7];  const float* b20 = (const float*)d_in[8];
    const float* w21 = (const float*)d_in[9];  const float* b21 = (const float*)d_in[10];
    const float* w22 = (const float*)d_in[11]; const float* b22 = (const float*)d_in[12];
    const float* w30 = (const float*)d_in[13]; const float* b30 = (const float*)d_in[14];
    const float* w31 = (const float*)d_in[15]; const float* b31 = (const float*)d_in[16];
    const float* w32 = (const float*)d_in[17]; const float* b32 = (const float*)d_in[18];
    float* out = (float*)d_out;

    char* ws = (char*)d_ws;
    size_t off = 0;
    auto alloc = [&](size_t bytes) -> void* {
        void* p = ws + off;
        off += (bytes + 255) & ~(size_t)255;
        return p;
    };
    float* nxz1 = (float*)alloc((size_t)BT * S1 * 3 * 4);
    float* nxz2 = (float*)alloc((size_t)BT * S2 * 3 * 4);
    unsigned short* wb  = (unsigned short*)alloc((size_t)823296 * 2);
    unsigned short* f1  = (unsigned short*)alloc((size_t)8192 * 128 * 2);
    unsigned short* f2  = (unsigned short*)alloc((size_t)4096 * 256 * 2);
    unsigned short* C1  = (unsigned short*)alloc((size_t)4096 * 256 * 2);
    unsigned short* C2  = (unsigned short*)alloc((size_t)4096 * 512 * 2);

    const unsigned short* w11b = wb + 0;
    const unsigned short* w12b = wb + 4096;
    const unsigned short* w20p = wb + 12288;
    const unsigned short* w21b = wb + 36864;
    const unsigned short* w22b = wb + 53248;
    const unsigned short* w30p = wb + 86016;
    const unsigned short* w31b = wb + 167936;
    const unsigned short* w32b = wb + 299008;

    // ---- L1: fps1 (blocks 0-31) + wconv (blocks 32-3247) ----
    fps1_wconv_kernel<<<32 + 3216, 256, 0, stream>>>(
        data, nxz1, w11, w12, w20, w21, w22, w30, w31, w32, wb);
    // ---- L2: fps2 (blocks 0-31, first) + m1 with inline ballq1 (blocks 32-2079) ----
    m1bq_fps2_kernel<<<32 + 2048, 256, 0, stream>>>(
        data, nxz1, w10, b10, w11b, b11, w12b, b12, f1, nxz2);
    // ---- L3: module 2 with inline ballq2 ----
    m2bq_kernel<<<131072 / 128, 256, 0, stream>>>(
        nxz1, nxz2, f1, w20p, b20, w21b, b21, w22b, b22, f2);
    // ---- L4-L6: module 3 ----
    l30_kernel<<<dim3(4096 / 128, 2), 256, 0, stream>>>(nxz2, f2, w30p, b30, C1);
    mfma_gemm<64><<<dim3(4096 / 64, 4), 256, 0, stream>>>(C1, w31b, b31, C2, 4096, 512, 256);
    gemm_pool128<<<dim3(4096 / 128, 8), 256, 0, stream>>>(C2, w32b, b32, out);
}

// Round 7
// 449.302 us; speedup vs baseline: 1.1252x; 1.1252x over previous
//
#include <hip/hip_runtime.h>
#include <hip/hip_bf16.h>
#include <cstdint>
#include <cstddef>

// Problem constants: data (4,8,4096,3) -> 32 batches x 4096 points
#define BT 32
#define N1 4096
#define S1 256
#define S2 128
#define KNB 32

typedef __attribute__((ext_vector_type(8))) short short8;   // 8 bf16 in 4 VGPRs
typedef __attribute__((ext_vector_type(4))) float f32x4;

__device__ __forceinline__ float sqdist(float ax, float ay, float az,
                                        float bx, float by, float bz) {
    // exact replication of sum((a-b)**2, axis=-1): mul then left-to-right add, NO fma
    float dx = __fsub_rn(ax, bx), dy = __fsub_rn(ay, by), dz = __fsub_rn(az, bz);
    return __fadd_rn(__fadd_rn(__fmul_rn(dx, dx), __fmul_rn(dy, dy)), __fmul_rn(dz, dz));
}

// bf16 round-to-nearest-even (values here are finite)
__device__ __forceinline__ unsigned short f2bf(float f) {
    unsigned u = __float_as_uint(f);
    return (unsigned short)((u + 0x7FFFu + ((u >> 16) & 1u)) >> 16);
}
__device__ __forceinline__ float bf2f(unsigned short h) {
    return __uint_as_float(((unsigned)h) << 16);
}

// pack (value, index) for argmax-with-first-index-tie-break: distances >= 0 so float
// bits are monotonic as uint; on equal value, larger ~idx == smaller idx wins.
__device__ __forceinline__ unsigned long long packvi(float v, int idx) {
    return ((unsigned long long)__float_as_uint(v) << 32) | (unsigned)(~idx);
}

// DPP row-rotate max for u64 (rotate within 16-lane rows; commutative reduce)
template <int CTRL>
__device__ __forceinline__ unsigned long long dppmax(unsigned long long v) {
    int lo = (int)(unsigned)(v & 0xFFFFFFFFull);
    int hi = (int)(unsigned)(v >> 32);
    int lo2 = __builtin_amdgcn_update_dpp(0, lo, CTRL, 0xF, 0xF, false);
    int hi2 = __builtin_amdgcn_update_dpp(0, hi, CTRL, 0xF, 0xF, false);
    unsigned long long o = ((unsigned long long)(unsigned)hi2 << 32) | (unsigned)lo2;
    return o > v ? o : v;
}
#define ROR1 0x121
#define ROR2 0x122
#define ROR4 0x124
#define ROR8 0x128

// wave-level ball query: scans X[0..n), radius^2 r2, writes KNB indices to gl[].
// EXACT semantics of the standalone kernel (ascending-index fill, first-hit pad).
// R18 LEDGER: the cnt<KNB loop condition is a loop-carried dependency (ballot feeds
// next iteration's issue) -> ~300cyc/iter serial chain. FINE standalone (TLP hides it,
// issue-bound ~13us); DISASTROUS fused into a 2-block/CU MFMA kernel over a long scan
// (R17: m1's 64-iter inline scan = +8us serial prologue per block, +56us total).
// Only fuse SHORT scans (m2's is 4 iters).
__device__ __forceinline__ void ballq_wave(const float* __restrict__ X, int n,
                                           float cx, float cy, float cz, float r2,
                                           int lane, int* __restrict__ gl) {
    int cnt = 0, first = 0;
    bool found = false;
    for (int j0 = 0; j0 < n && cnt < KNB; j0 += 64) {
        int j = j0 + lane;
        float d2 = sqdist(cx, cy, cz, X[j * 3 + 0], X[j * 3 + 1], X[j * 3 + 2]);
        bool hit = d2 < r2;
        unsigned long long mask = __ballot(hit);
        if (!found && mask) { first = j0 + __builtin_ctzll(mask); found = true; }
        if (hit) {
            int pos = cnt + __popcll(mask & ((1ull << lane) - 1ull));
            if (pos < KNB) gl[pos] = j;
        }
        cnt += __popcll(mask);
    }
    if (cnt < KNB) {
        int pad = found ? first : 0;
        if (lane >= cnt && lane < KNB) gl[lane] = pad;
    }
}

// ---------------- FPS module 1 + wconv PACKED into one launch (R15, kept) -----------
// fps1: blocks 0..31 (one per batch, EXACT byte-for-byte R8/R9/R11-proven 153us code).
// wconv: blocks 32..3247 (~5us + launch gap hidden under fps1's 153us serial chain).
// FPS DO-NOT-TOUCH ledger (all measured equal or worse): 512-thr (per-CU issue-bound),
// payload-DPP reduce, coord-prefetch, single-slot LDS atomicMax (R13: +65us, DS
// serializes same-address RMW), f32x2 pk math (R14: +49us, v_pk_*_f32 has NO
// issue-rate gain on CDNA4), tree argmax (R14, part of +49us).
// fps1 per-iter critical path ~1440cyc = compute ~400 + sync chain ~1000 — structural
// for 4-wave cross-wave argmax; accepted.
//
//  w11b@0      64x64   | w12b@4096  128x64 | w20p@12288 128x192 (PERM: feat-first)
//  w21b@36864  128x128 | w22b@53248 256x128| w30p@86016 256x320 (PERM: feat-first)
//  w31b@167936 512x256 | w32b@299008 1024x512  total 823296
__global__ __launch_bounds__(256) void fps1_wconv_kernel(
    const float* __restrict__ xyz, float* __restrict__ nxz,
    const float* __restrict__ w11, const float* __restrict__ w12,
    const float* __restrict__ w20, const float* __restrict__ w21,
    const float* __restrict__ w22, const float* __restrict__ w30,
    const float* __restrict__ w31, const float* __restrict__ w32,
    unsigned short* __restrict__ wb) {
    if (blockIdx.x < 32) {
        // ================= fps1 (EXACT proven code, b = blockIdx.x) =================
        const int b = blockIdx.x, tid = threadIdx.x;
        const int lane = tid & 63, wv = tid >> 6;      // 4 waves
        const float* X = xyz + (size_t)b * (N1 * 3);
        __shared__ float4 s4[N1];                      // 64 KB
        __shared__ unsigned long long slots[2][16];
        __shared__ float hist[S1 * 3];
        float px[16], py[16], pz[16], md[16];
        int bidx[16];
#pragma unroll
        for (int j = 0; j < 16; ++j) {
            int i = tid + 256 * j;
            float x = X[i * 3 + 0], y = X[i * 3 + 1], z = X[i * 3 + 2];
            s4[i] = make_float4(x, y, z, 0.f);
            px[j] = x; py[j] = y; pz[j] = z;
            md[j] = 1e10f;
            bidx[j] = i;
        }
        if (tid == 0) { hist[0] = X[0]; hist[1] = X[1]; hist[2] = X[2]; }
        __syncthreads();
        float4 c0 = s4[0];
        float lx = c0.x, ly = c0.y, lz = c0.z;
        for (int t = 1; t < S1; ++t) {
            float bv = -1.0f; int bi = 0;
#pragma unroll
            for (int j = 0; j < 16; ++j) {
                float d = sqdist(px[j], py[j], pz[j], lx, ly, lz);
                float m = fminf(md[j], d);
                md[j] = m;
                if (m > bv) { bv = m; bi = bidx[j]; }   // ascending flat idx: first max kept
            }
            unsigned long long best = packvi(bv, bi);
            best = dppmax<ROR1>(best);
            best = dppmax<ROR2>(best);
            best = dppmax<ROR4>(best);
            best = dppmax<ROR8>(best);                  // row (16-lane) max
            if ((lane & 15) == 0) slots[t & 1][wv * 4 + (lane >> 4)] = best;
            __syncthreads();
            unsigned long long w = slots[t & 1][lane & 15];
            w = dppmax<ROR1>(w);
            w = dppmax<ROR2>(w);
            w = dppmax<ROR4>(w);
            w = dppmax<ROR8>(w);
            int vi = (int)(~(unsigned)w);
            float4 c = s4[vi];
            lx = c.x; ly = c.y; lz = c.z;
            if (tid == 0) { hist[t * 3 + 0] = lx; hist[t * 3 + 1] = ly; hist[t * 3 + 2] = lz; }
        }
        __syncthreads();
        for (int u = tid; u < S1 * 3; u += 256) nxz[(size_t)b * S1 * 3 + u] = hist[u];
    } else {
        // ================= wconv (blocks 32..3247; u covers 0..823295) ==============
        int u = (blockIdx.x - 32) * 256 + threadIdx.x;
        if (u >= 823296) return;
        const float* src; int base, Kp, Ko; int perm = 0;   // perm: feature-count, feat-first
        if      (u < 4096)   { src = w11; base = 0;      Kp = 64;  Ko = 64;  }
        else if (u < 12288)  { src = w12; base = 4096;   Kp = 64;  Ko = 64;  }
        else if (u < 36864)  { src = w20; base = 12288;  Kp = 192; Ko = 131; perm = 128; }
        else if (u < 53248)  { src = w21; base = 36864;  Kp = 128; Ko = 128; }
        else if (u < 86016)  { src = w22; base = 53248;  Kp = 128; Ko = 128; }
        else if (u < 167936) { src = w30; base = 86016;  Kp = 320; Ko = 259; perm = 256; }
        else if (u < 299008) { src = w31; base = 167936; Kp = 256; Ko = 256; }
        else                 { src = w32; base = 299008; Kp = 512; Ko = 512; }
        int local = u - base;
        int n = local / Kp, k = local - n * Kp;
        float v;
        if (perm) {
            int ksrc = (k < perm) ? (k + 3) : ((k < perm + 3) ? (k - perm) : -1);
            v = (ksrc >= 0) ? src[(size_t)n * Ko + ksrc] : 0.f;
        } else {
            v = (k < Ko) ? src[(size_t)n * Ko + k] : 0.f;
        }
        wb[u] = f2bf(v);
    }
}

// ---------------- Ball query 1 STANDALONE (R18: restored from R16) -------------------
// Stays standalone: high-occupancy launch hides the ballot dependency chain (~13us,
// issue-bound). Fusing it into m1 was R17's +56us regression.
__global__ __launch_bounds__(256) void ballq1_kernel(const float* __restrict__ xyz,
                                                     const float* __restrict__ nxz,
                                                     int* __restrict__ gidx) {
    const int wid = (blockIdx.x * 256 + threadIdx.x) >> 6;
    const int lane = threadIdx.x & 63;
    const int b = wid >> 8;
    ballq_wave(xyz + (size_t)b * (N1 * 3), N1,
               nxz[(size_t)wid * 3 + 0], nxz[(size_t)wid * 3 + 1], nxz[(size_t)wid * 3 + 2],
               (float)(0.2 * 0.2), lane, gidx + (size_t)wid * KNB);
}

// ---------------- L3: fps2 + m1 PACKED (R16 structure, restored) ---------------------
// fps2 (blocks 0..31, first): 26us serial chain, hidden under m1.
// m1 (blocks 32..2079): gathers via g1 from the standalone ballq1 launch.
__global__ __launch_bounds__(256) void m1_fps2_kernel(
    const float* __restrict__ xyz, const float* __restrict__ nxz,
    const int* __restrict__ g1,
    const float* __restrict__ w10, const float* __restrict__ b10,
    const unsigned short* __restrict__ w11b, const float* __restrict__ b11,
    const unsigned short* __restrict__ w12b, const float* __restrict__ b12,
    unsigned short* __restrict__ f1,
    float* __restrict__ nxz2) {
    if (blockIdx.x < 32) {
        // ================= fps2 (one wave per batch; threads 64..255 exit) ==========
        if (threadIdx.x >= 64) return;
        const int b = blockIdx.x, lane = threadIdx.x;
        const float* X = nxz + (size_t)b * (S1 * 3);
        __shared__ float4 s4f[S1];
        float px[4], py[4], pz[4], md[4];
        int bidx[4];
#pragma unroll
        for (int j = 0; j < 4; ++j) {
            int i = lane + 64 * j;
            float x = X[i * 3 + 0], y = X[i * 3 + 1], z = X[i * 3 + 2];
            s4f[i] = make_float4(x, y, z, 0.f);
            px[j] = x; py[j] = y; pz[j] = z;
            md[j] = 1e10f;
            bidx[j] = i;
        }
        if (lane == 0) {
            nxz2[(size_t)b * S2 * 3 + 0] = X[0];
            nxz2[(size_t)b * S2 * 3 + 1] = X[1];
            nxz2[(size_t)b * S2 * 3 + 2] = X[2];
        }
        // single wave: LDS writes above are wave-synchronous
        float4 cc = s4f[0];
        float lx = cc.x, ly = cc.y, lz = cc.z;
        for (int t = 1; t < S2; ++t) {
            float bv = -1.0f; int bi = 0;
#pragma unroll
            for (int j = 0; j < 4; ++j) {
                float d = sqdist(px[j], py[j], pz[j], lx, ly, lz);
                float m = fminf(md[j], d);
                md[j] = m;
                if (m > bv) { bv = m; bi = bidx[j]; }
            }
            unsigned long long best = packvi(bv, bi);
            best = dppmax<ROR1>(best);
            best = dppmax<ROR2>(best);
            best = dppmax<ROR4>(best);
            best = dppmax<ROR8>(best);
            { unsigned long long o = __shfl_xor(best, 16); best = o > best ? o : best; }
            { unsigned long long o = __shfl_xor(best, 32); best = o > best ? o : best; }
            int vi = (int)(~(unsigned)best);
            float4 c = s4f[vi];
            lx = c.x; ly = c.y; lz = c.z;
            if (lane == 0) {
                float* dst = nxz2 + ((size_t)b * S2 + t) * 3;
                dst[0] = lx; dst[1] = ly; dst[2] = lz;
            }
        }
        return;
    }
    // ================= m1 (blocks 32..2079) =========================================
    constexpr int AP = 72;
    __shared__ __align__(16) unsigned short As[128 * AP];
    __shared__ __align__(16) unsigned short Hs[128 * AP];
    __shared__ __align__(16) unsigned short Bs[192 * AP];   // w11 (64 rows) + w12 (128 rows)
    __shared__ float sxyz[128 * 3];
    const int t = threadIdx.x;
    const int lane = t & 63, w = t >> 6;
    const int r16 = lane & 15, q = lane >> 4;
    const int m0 = (blockIdx.x - 32) * 128;

    if (t < 128) {
        int row = m0 + t, bs = row >> 5, b = bs >> 8, j = g1[row];
        const float* P = xyz + ((size_t)b * N1 + j) * 3;
        const float* Cc = nxz + (size_t)bs * 3;
        sxyz[t * 3 + 0] = P[0] - Cc[0];
        sxyz[t * 3 + 1] = P[1] - Cc[1];
        sxyz[t * 3 + 2] = P[2] - Cc[2];
    }
    // stage w11 (rows 0..63) and w12 (rows 64..191) in one pass
    for (int c = t; c < 192 * 8; c += 256) {
        int row = c >> 3, ch = c & 7;
        const unsigned short* src = (row < 64) ? &w11b[row * 64 + ch * 8]
                                               : &w12b[(row - 64) * 64 + ch * 8];
        *(short8*)&Bs[row * AP + ch * 8] = *(const short8*)src;
    }
    __syncthreads();
    {
        const int r = t >> 1, half = (t & 1) * 32;
        const float x = sxyz[r * 3 + 0], y = sxyz[r * 3 + 1], z = sxyz[r * 3 + 2];
        unsigned short tmp[32];
#pragma unroll
        for (int o = 0; o < 32; ++o) {
            int oo = half + o;
            float acc = b10[oo];
            acc = fmaf(x, w10[oo * 3 + 0], acc);
            acc = fmaf(y, w10[oo * 3 + 1], acc);
            acc = fmaf(z, w10[oo * 3 + 2], acc);
            tmp[o] = f2bf(fmaxf(acc, 0.f));
        }
#pragma unroll
        for (int c2 = 0; c2 < 4; ++c2)
            *(short8*)&As[r * AP + half + c2 * 8] = *(short8*)&tmp[c2 * 8];
    }
    __syncthreads();
    {
        f32x4 acc[2][4];
#pragma unroll
        for (int i = 0; i < 2; ++i)
#pragma unroll
            for (int j = 0; j < 4; ++j) acc[i][j] = (f32x4){0.f, 0.f, 0.f, 0.f};
#pragma unroll
        for (int kk = 0; kk < 64; kk += 32) {
            short8 a0 = *(const short8*)&As[(w * 32 + r16) * AP + kk + q * 8];
            short8 a1 = *(const short8*)&As[(w * 32 + 16 + r16) * AP + kk + q * 8];
#pragma unroll
            for (int j = 0; j < 4; ++j) {
                short8 bf = *(const short8*)&Bs[(j * 16 + r16) * AP + kk + q * 8];
                acc[0][j] = __builtin_amdgcn_mfma_f32_16x16x32_bf16(a0, bf, acc[0][j], 0, 0, 0);
                acc[1][j] = __builtin_amdgcn_mfma_f32_16x16x32_bf16(a1, bf, acc[1][j], 0, 0, 0);
            }
        }
#pragma unroll
        for (int i = 0; i < 2; ++i)
#pragma unroll
            for (int j = 0; j < 4; ++j) {
                int col = j * 16 + r16;
                float bv = b11[col];
#pragma unroll
                for (int r = 0; r < 4; ++r) {
                    int row = w * 32 + i * 16 + q * 4 + r;
                    Hs[row * AP + col] = f2bf(fmaxf(acc[i][j][r] + bv, 0.f));
                }
            }
    }
    __syncthreads();   // Hs fully written; Bs rows 64.. already hold w12
    {
        f32x4 acc[2][8];
#pragma unroll
        for (int i = 0; i < 2; ++i)
#pragma unroll
            for (int j = 0; j < 8; ++j) acc[i][j] = (f32x4){0.f, 0.f, 0.f, 0.f};
#pragma unroll
        for (int kk = 0; kk < 64; kk += 32) {
            short8 a0 = *(const short8*)&Hs[(w * 32 + r16) * AP + kk + q * 8];
            short8 a1 = *(const short8*)&Hs[(w * 32 + 16 + r16) * AP + kk + q * 8];
#pragma unroll
            for (int j = 0; j < 8; ++j) {
                short8 bf = *(const short8*)&Bs[(64 + j * 16 + r16) * AP + kk + q * 8];
                acc[0][j] = __builtin_amdgcn_mfma_f32_16x16x32_bf16(a0, bf, acc[0][j], 0, 0, 0);
                acc[1][j] = __builtin_amdgcn_mfma_f32_16x16x32_bf16(a1, bf, acc[1][j], 0, 0, 0);
            }
        }
#pragma unroll
        for (int j = 0; j < 8; ++j) {
            int col = j * 16 + r16;
            float bv = b12[col];
            float mv = 0.f;
#pragma unroll
            for (int i = 0; i < 2; ++i)
#pragma unroll
                for (int r = 0; r < 4; ++r)
                    mv = fmaxf(mv, acc[i][j][r] + bv);
            mv = fmaxf(mv, __shfl_xor(mv, 16));
            mv = fmaxf(mv, __shfl_xor(mv, 32));
            if (q == 0)
                f1[(size_t)((m0 >> 5) + w) * 128 + col] = f2bf(mv);
        }
    }
}

// ---------------- L4: Module 2 fully fused + INLINE ballq2 (R17 m2bq, kept) ----------
// ballq2's scan is only 4 iterations over S1=256 L2-hot points (~1.2K cyc serial per
// block) — 16x shorter than m1's, so fusing it is cheap and removes a launch + gap.
// R12 core kept: w21 staged into R1 in ONE pass.
__global__ __launch_bounds__(256) void m2bq_kernel(
    const float* __restrict__ xyz1, const float* __restrict__ nxz2,
    const unsigned short* __restrict__ f1,
    const unsigned short* __restrict__ w20p, const float* __restrict__ b20,
    const unsigned short* __restrict__ w21b, const float* __restrict__ b21,
    const unsigned short* __restrict__ w22b, const float* __restrict__ b22,
    unsigned short* __restrict__ f2) {
    constexpr int AP = 72, HP = 136;
    __shared__ __align__(16) unsigned short smem[36864];   // 72 KB
    unsigned short* R1 = smem;
    unsigned short* R2 = smem + 18432;
    unsigned short* As = R1;
    unsigned short* Bs = R1 + 9216;
    unsigned short* W21 = R1;            // full w21, stride HP (17408 shorts)
    unsigned short* H1 = R2;
    unsigned short* H2 = R1;
    unsigned short* Bs2 = R2;
    __shared__ int ribase[128];
    __shared__ unsigned short sxb[128 * 3];
    __shared__ int gl2[4][KNB];
    const int t = threadIdx.x;
    const int lane = t & 63, w = t >> 6;
    const int r16 = lane & 15, q = lane >> 4;
    const int m0 = blockIdx.x * 128;

    // ---- inline ballq2: wave w computes center (m0>>5)+w's 32-neighbor list ----
    {
        const int cs = (m0 >> 5) + w;          // global center id [0,4096)
        const int bb = cs >> 7;
        const float* Cc = nxz2 + (size_t)cs * 3;
        ballq_wave(xyz1 + (size_t)bb * (S1 * 3), S1,
                   Cc[0], Cc[1], Cc[2], (float)(0.4 * 0.4), lane, gl2[w]);
    }
    __syncthreads();                            // gl2 ready for cross-wave gather
    if (t < 128) {
        int row = m0 + t, bs = row >> 5, b = bs >> 7, j = gl2[t >> 5][t & 31];
        ribase[t] = (b * 256 + j) * 128;
        const float* P = xyz1 + ((size_t)b * S1 + j) * 3;
        const float* Cc = nxz2 + (size_t)bs * 3;
        sxb[t * 3 + 0] = f2bf(P[0] - Cc[0]);
        sxb[t * 3 + 1] = f2bf(P[1] - Cc[1]);
        sxb[t * 3 + 2] = f2bf(P[2] - Cc[2]);
    }
    __syncthreads();

    // ---- L0: K=192 (3 tiles), N=128 ----
    f32x4 acc[2][8];
#pragma unroll
    for (int i = 0; i < 2; ++i)
#pragma unroll
        for (int j = 0; j < 8; ++j) acc[i][j] = (f32x4){0.f, 0.f, 0.f, 0.f};
    for (int kt = 0; kt < 3; ++kt) {
        const int k0 = kt * 64;
        if (kt < 2) {
            for (int c = t; c < 128 * 8; c += 256) {
                int row = c >> 3, ch = c & 7;
                *(short8*)&As[row * AP + ch * 8] =
                    *(const short8*)&f1[(size_t)ribase[row] + k0 + ch * 8];
            }
        } else {
            for (int c = t; c < 128 * 8; c += 256) {
                int row = c >> 3, ch = c & 7;
                short8 v = (short8){0, 0, 0, 0, 0, 0, 0, 0};
                if (ch == 0) {
                    v[0] = (short)sxb[row * 3 + 0];
                    v[1] = (short)sxb[row * 3 + 1];
                    v[2] = (short)sxb[row * 3 + 2];
                }
                *(short8*)&As[row * AP + ch * 8] = v;
            }
        }
        for (int c = t; c < 128 * 8; c += 256) {
            int row = c >> 3, ch = c & 7;
            *(short8*)&Bs[row * AP + ch * 8] =
                *(const short8*)&w20p[(size_t)row * 192 + k0 + ch * 8];
        }
        __syncthreads();
#pragma unroll
        for (int kk = 0; kk < 64; kk += 32) {
            short8 a0 = *(const short8*)&As[(w * 32 + r16) * AP + kk + q * 8];
            short8 a1 = *(const short8*)&As[(w * 32 + 16 + r16) * AP + kk + q * 8];
#pragma unroll
            for (int j = 0; j < 8; ++j) {
                short8 bf = *(const short8*)&Bs[(j * 16 + r16) * AP + kk + q * 8];
                acc[0][j] = __builtin_amdgcn_mfma_f32_16x16x32_bf16(a0, bf, acc[0][j], 0, 0, 0);
                acc[1][j] = __builtin_amdgcn_mfma_f32_16x16x32_bf16(a1, bf, acc[1][j], 0, 0, 0);
            }
        }
        __syncthreads();
    }
#pragma unroll
    for (int i = 0; i < 2; ++i)
#pragma unroll
        for (int j = 0; j < 8; ++j) {
            int col = j * 16 + r16;
            float bv = b20[col];
#pragma unroll
            for (int r = 0; r < 4; ++r) {
                int row = w * 32 + i * 16 + q * 4 + r;
                H1[row * HP + col] = f2bf(fmaxf(acc[i][j][r] + bv, 0.f));
            }
        }
    // ---- L1: K=128, N=128; stage FULL w21 into R1 (As/Bs dead), single barrier ----
    __syncthreads();
    for (int c = t; c < 128 * 16; c += 256) {
        int row = c >> 4, ch = c & 15;
        *(short8*)&W21[row * HP + ch * 8] =
            *(const short8*)&w21b[(size_t)row * 128 + ch * 8];
    }
    __syncthreads();
#pragma unroll
    for (int i = 0; i < 2; ++i)
#pragma unroll
        for (int j = 0; j < 8; ++j) acc[i][j] = (f32x4){0.f, 0.f, 0.f, 0.f};
#pragma unroll
    for (int kk = 0; kk < 128; kk += 32) {
        short8 a0 = *(const short8*)&H1[(w * 32 + r16) * HP + kk + q * 8];
        short8 a1 = *(const short8*)&H1[(w * 32 + 16 + r16) * HP + kk + q * 8];
#pragma unroll
        for (int j = 0; j < 8; ++j) {
            short8 bf = *(const short8*)&W21[(j * 16 + r16) * HP + kk + q * 8];
            acc[0][j] = __builtin_amdgcn_mfma_f32_16x16x32_bf16(a0, bf, acc[0][j], 0, 0, 0);
            acc[1][j] = __builtin_amdgcn_mfma_f32_16x16x32_bf16(a1, bf, acc[1][j], 0, 0, 0);
        }
    }
    __syncthreads();   // all waves done reading W21 (R1); H2 overwrites R1
#pragma unroll
    for (int i = 0; i < 2; ++i)
#pragma unroll
        for (int j = 0; j < 8; ++j) {
            int col = j * 16 + r16;
            float bv = b21[col];
#pragma unroll
            for (int r = 0; r < 4; ++r) {
                int row = w * 32 + i * 16 + q * 4 + r;
                H2[row * HP + col] = f2bf(fmaxf(acc[i][j][r] + bv, 0.f));
            }
        }
    __syncthreads();

    // ---- L2: K=128 (2 tiles), N=256 + pool ----
    f32x4 acc2[2][16];
#pragma unroll
    for (int i = 0; i < 2; ++i)
#pragma unroll
        for (int j = 0; j < 16; ++j) acc2[i][j] = (f32x4){0.f, 0.f, 0.f, 0.f};
    for (int kt = 0; kt < 2; ++kt) {
        const int k0 = kt * 64;
        for (int c = t; c < 256 * 8; c += 256) {
            int row = c >> 3, ch = c & 7;
            *(short8*)&Bs2[row * AP + ch * 8] =
                *(const short8*)&w22b[(size_t)row * 128 + k0 + ch * 8];
        }
        __syncthreads();
#pragma unroll
        for (int kk = 0; kk < 64; kk += 32) {
            short8 a0 = *(const short8*)&H2[(w * 32 + r16) * HP + k0 + kk + q * 8];
            short8 a1 = *(const short8*)&H2[(w * 32 + 16 + r16) * HP + k0 + kk + q * 8];
#pragma unroll
            for (int j = 0; j < 16; ++j) {
                short8 bf = *(const short8*)&Bs2[(j * 16 + r16) * AP + kk + q * 8];
                acc2[0][j] = __builtin_amdgcn_mfma_f32_16x16x32_bf16(a0, bf, acc2[0][j], 0, 0, 0);
                acc2[1][j] = __builtin_amdgcn_mfma_f32_16x16x32_bf16(a1, bf, acc2[1][j], 0, 0, 0);
            }
        }
        __syncthreads();
    }
#pragma unroll
    for (int j = 0; j < 16; ++j) {
        int col = j * 16 + r16;
        float bv = b22[col];
        float mv = 0.f;
#pragma unroll
        for (int i = 0; i < 2; ++i)
#pragma unroll
            for (int r = 0; r < 4; ++r)
                mv = fmaxf(mv, acc2[i][j][r] + bv);
        mv = fmaxf(mv, __shfl_xor(mv, 16));
        mv = fmaxf(mv, __shfl_xor(mv, 32));
        if (q == 0)
            f2[(size_t)((m0 >> 5) + w) * 256 + col] = f2bf(mv);
    }
}

// ---------------- Module 3 layer 0 with fused concat (feat-first K=320) ---------------
__global__ __launch_bounds__(256) void l30_kernel(
    const float* __restrict__ nxz2, const unsigned short* __restrict__ f2,
    const unsigned short* __restrict__ w30p, const float* __restrict__ bias,
    unsigned short* __restrict__ C) {
    constexpr int AP = 72;
    __shared__ __align__(16) unsigned short As[128 * AP];
    __shared__ __align__(16) unsigned short Bs[128 * AP];
    const int t = threadIdx.x;
    const int lane = t & 63, w = t >> 6;
    const int r16 = lane & 15, q = lane >> 4;
    const int m0 = blockIdx.x * 128;
    const int n0 = blockIdx.y * 128;

    f32x4 acc[2][8];
#pragma unroll
    for (int i = 0; i < 2; ++i)
#pragma unroll
        for (int j = 0; j < 8; ++j) acc[i][j] = (f32x4){0.f, 0.f, 0.f, 0.f};

    for (int kt = 0; kt < 5; ++kt) {
        const int k0 = kt * 64;
        if (kt < 4) {
            for (int c = t; c < 128 * 8; c += 256) {
                int row = c >> 3, ch = c & 7;
                *(short8*)&As[row * AP + ch * 8] =
                    *(const short8*)&f2[(size_t)(m0 + row) * 256 + k0 + ch * 8];
            }
        } else {
            for (int c = t; c < 128 * 8; c += 256) {
                int row = c >> 3, ch = c & 7;
                short8 v = (short8){0, 0, 0, 0, 0, 0, 0, 0};
                if (ch == 0) {
                    const float* P = nxz2 + (size_t)(m0 + row) * 3;
                    v[0] = (short)f2bf(P[0]);
                    v[1] = (short)f2bf(P[1]);
                    v[2] = (short)f2bf(P[2]);
                }
                *(short8*)&As[row * AP + ch * 8] = v;
            }
        }
        for (int c = t; c < 128 * 8; c += 256) {
            int row = c >> 3, ch = c & 7;
            *(short8*)&Bs[row * AP + ch * 8] =
                *(const short8*)&w30p[(size_t)(n0 + row) * 320 + k0 + ch * 8];
        }
        __syncthreads();
#pragma unroll
        for (int kk = 0; kk < 64; kk += 32) {
            short8 a0 = *(const short8*)&As[(w * 32 + r16) * AP + kk + q * 8];
            short8 a1 = *(const short8*)&As[(w * 32 + 16 + r16) * AP + kk + q * 8];
#pragma unroll
            for (int j = 0; j < 8; ++j) {
                short8 bf = *(const short8*)&Bs[(j * 16 + r16) * AP + kk + q * 8];
                acc[0][j] = __builtin_amdgcn_mfma_f32_16x16x32_bf16(a0, bf, acc[0][j], 0, 0, 0);
                acc[1][j] = __builtin_amdgcn_mfma_f32_16x16x32_bf16(a1, bf, acc[1][j], 0, 0, 0);
            }
        }
        __syncthreads();
    }
#pragma unroll
    for (int i = 0; i < 2; ++i)
#pragma unroll
        for (int j = 0; j < 8; ++j) {
            int col = n0 + j * 16 + r16;
            float bv = bias[col];
#pragma unroll
            for (int r = 0; r < 4; ++r) {
                int row = m0 + w * 32 + i * 16 + q * 4 + r;
                C[(size_t)row * 256 + col] = f2bf(fmaxf(acc[i][j][r] + bv, 0.f));
            }
        }
}

// ---------------- bf16 MFMA GEMM (BM templated): C = relu(X*W^T + bias), BN=128 --------
template <int BM_>
__global__ __launch_bounds__(256) void mfma_gemm(const unsigned short* __restrict__ X,
                                                 const unsigned short* __restrict__ W,
                                                 const float* __restrict__ bias,
                                                 unsigned short* __restrict__ C,
                                                 int M, int N, int K) {
    constexpr int BK = 64, AP = BK + 8;
    constexpr int RW = BM_ / 64;         // M-frags per wave
    constexpr int WR = BM_ / 4;          // rows per wave
    __shared__ __align__(16) unsigned short As[BM_ * AP];
    __shared__ __align__(16) unsigned short Bs[128 * AP];
    const int t = threadIdx.x;
    const int lane = t & 63, w = t >> 6;
    const int m0 = blockIdx.x * BM_;
    const int n0 = blockIdx.y * 128;
    const int r16 = lane & 15, q = lane >> 4;

    f32x4 acc[RW][8];
#pragma unroll
    for (int i = 0; i < RW; ++i)
#pragma unroll
        for (int j = 0; j < 8; ++j) acc[i][j] = (f32x4){0.f, 0.f, 0.f, 0.f};

    for (int k0 = 0; k0 < K; k0 += BK) {
        for (int c = t; c < BM_ * 8; c += 256) {
            int row = c >> 3, ch = c & 7;
            *(short8*)&As[row * AP + ch * 8] =
                *(const short8*)&X[(size_t)(m0 + row) * K + k0 + ch * 8];
        }
        for (int c = t; c < 128 * 8; c += 256) {
            int row = c >> 3, ch = c & 7;
            *(short8*)&Bs[row * AP + ch * 8] =
                *(const short8*)&W[(size_t)(n0 + row) * K + k0 + ch * 8];
        }
        __syncthreads();
#pragma unroll
        for (int kk = 0; kk < BK; kk += 32) {
            short8 a[RW];
#pragma unroll
            for (int i = 0; i < RW; ++i)
                a[i] = *(const short8*)&As[(w * WR + i * 16 + r16) * AP + kk + q * 8];
#pragma unroll
            for (int j = 0; j < 8; ++j) {
                short8 bf = *(const short8*)&Bs[(j * 16 + r16) * AP + kk + q * 8];
#pragma unroll
                for (int i = 0; i < RW; ++i)
                    acc[i][j] = __builtin_amdgcn_mfma_f32_16x16x32_bf16(a[i], bf, acc[i][j], 0, 0, 0);
            }
        }
        __syncthreads();
    }
#pragma unroll
    for (int i = 0; i < RW; ++i)
#pragma unroll
        for (int j = 0; j < 8; ++j) {
            int col = n0 + j * 16 + r16;
            float bv = bias[col];
#pragma unroll
            for (int r = 0; r < 4; ++r) {
                int row = m0 + w * WR + i * 16 + q * 4 + r;
                C[(size_t)row * N + col] = f2bf(fmaxf(acc[i][j][r] + bv, 0.f));
            }
        }
}

// ---------------- Final GEMM (N=1024, K=512) + max over 128 rows -> fp32 out ----------
__global__ __launch_bounds__(256) void gemm_pool128(const unsigned short* __restrict__ X,
                                                    const unsigned short* __restrict__ W,
                                                    const float* __restrict__ bias,
                                                    float* __restrict__ out) {
    constexpr int BK = 64, AP = BK + 8, K = 512;
    __shared__ __align__(16) unsigned short As[128 * AP];
    __shared__ __align__(16) unsigned short Bs[128 * AP];
    __shared__ float pool[4][128];
    const int t = threadIdx.x;
    const int lane = t & 63, w = t >> 6;
    const int m0 = blockIdx.x * 128;
    const int n0 = blockIdx.y * 128;
    const int r16 = lane & 15, q = lane >> 4;

    f32x4 acc[2][8];
#pragma unroll
    for (int i = 0; i < 2; ++i)
#pragma unroll
        for (int j = 0; j < 8; ++j) acc[i][j] = (f32x4){0.f, 0.f, 0.f, 0.f};

    for (int k0 = 0; k0 < K; k0 += BK) {
        for (int c = t; c < 128 * 8; c += 256) {
            int row = c >> 3, ch = c & 7;
            *(short8*)&As[row * AP + ch * 8] =
                *(const short8*)&X[(size_t)(m0 + row) * K + k0 + ch * 8];
        }
        for (int c = t; c < 128 * 8; c += 256) {
            int row = c >> 3, ch = c & 7;
            *(short8*)&Bs[row * AP + ch * 8] =
                *(const short8*)&W[(size_t)(n0 + row) * K + k0 + ch * 8];
        }
        __syncthreads();
#pragma unroll
        for (int kk = 0; kk < BK; kk += 32) {
            short8 a0 = *(const short8*)&As[(w * 32 + r16) * AP + kk + q * 8];
            short8 a1 = *(const short8*)&As[(w * 32 + 16 + r16) * AP + kk + q * 8];
#pragma unroll
            for (int j = 0; j < 8; ++j) {
                short8 bf = *(const short8*)&Bs[(j * 16 + r16) * AP + kk + q * 8];
                acc[0][j] = __builtin_amdgcn_mfma_f32_16x16x32_bf16(a0, bf, acc[0][j], 0, 0, 0);
                acc[1][j] = __builtin_amdgcn_mfma_f32_16x16x32_bf16(a1, bf, acc[1][j], 0, 0, 0);
            }
        }
        __syncthreads();
    }
    // wave-level pool over its 32 rows (relu via 0-init), then cross-wave via LDS
#pragma unroll
    for (int j = 0; j < 8; ++j) {
        float bv = bias[n0 + j * 16 + r16];
        float mv = 0.f;
#pragma unroll
        for (int i = 0; i < 2; ++i)
#pragma unroll
            for (int r = 0; r < 4; ++r)
                mv = fmaxf(mv, acc[i][j][r] + bv);
        mv = fmaxf(mv, __shfl_xor(mv, 16));
        mv = fmaxf(mv, __shfl_xor(mv, 32));
        if (q == 0) pool[w][j * 16 + r16] = mv;
    }
    __syncthreads();
    if (t < 128) {
        float m = fmaxf(fmaxf(pool[0][t], pool[1][t]), fmaxf(pool[2][t], pool[3][t]));
        out[(size_t)blockIdx.x * 1024 + n0 + t] = m;
    }
}

extern "C" void kernel_launch(void* const* d_in, const int* in_sizes, int n_in,
                              void* d_out, int out_size, void* d_ws, size_t ws_size,
                              hipStream_t stream) {
    const float* data = (const float*)d_in[0];
    const float* w10 = (const float*)d_in[1];  const float* b10 = (const float*)d_in[2];
    const float* w11 = (const float*)d_in[3];  const float* b11 = (const float*)d_in[4];
    const float* w12 = (const float*)d_in[5];  const float* b12 = (const float*)d_in[6];
    const float* w20 = (const float*)d_in[7];  const float* b20 = (const float*)d_in[8];
    const float* w21 = (const float*)d_in[9];  const float* b21 = (const float*)d_in[10];
    const float* w22 = (const float*)d_in[11]; const float* b22 = (const float*)d_in[12];
    const float* w30 = (const float*)d_in[13]; const float* b30 = (const float*)d_in[14];
    const float* w31 = (const float*)d_in[15]; const float* b31 = (const float*)d_in[16];
    const float* w32 = (const float*)d_in[17]; const float* b32 = (const float*)d_in[18];
    float* out = (float*)d_out;

    char* ws = (char*)d_ws;
    size_t off = 0;
    auto alloc = [&](size_t bytes) -> void* {
        void* p = ws + off;
        off += (bytes + 255) & ~(size_t)255;
        return p;
    };
    float* nxz1 = (float*)alloc((size_t)BT * S1 * 3 * 4);
    int*   g1   = (int*)  alloc((size_t)BT * S1 * KNB * 4);
    float* nxz2 = (float*)alloc((size_t)BT * S2 * 3 * 4);
    unsigned short* wb  = (unsigned short*)alloc((size_t)823296 * 2);
    unsigned short* f1  = (unsigned short*)alloc((size_t)8192 * 128 * 2);
    unsigned short* f2  = (unsigned short*)alloc((size_t)4096 * 256 * 2);
    unsigned short* C1  = (unsigned short*)alloc((size_t)4096 * 256 * 2);
    unsigned short* C2  = (unsigned short*)alloc((size_t)4096 * 512 * 2);

    const unsigned short* w11b = wb + 0;
    const unsigned short* w12b = wb + 4096;
    const unsigned short* w20p = wb + 12288;
    const unsigned short* w21b = wb + 36864;
    const unsigned short* w22b = wb + 53248;
    const unsigned short* w30p = wb + 86016;
    const unsigned short* w31b = wb + 167936;
    const unsigned short* w32b = wb + 299008;

    // ---- L1: fps1 (blocks 0-31) + wconv (blocks 32-3247) ----
    fps1_wconv_kernel<<<32 + 3216, 256, 0, stream>>>(
        data, nxz1, w11, w12, w20, w21, w22, w30, w31, w32, wb);
    // ---- L2: ballq1 standalone (high occupancy hides ballot dep-chain) ----
    ballq1_kernel<<<(BT * S1) / 4, 256, 0, stream>>>(data, nxz1, g1);
    // ---- L3: fps2 (blocks 0-31, first) + m1 (blocks 32-2079) ----
    m1_fps2_kernel<<<32 + 2048, 256, 0, stream>>>(
        data, nxz1, g1, w10, b10, w11b, b11, w12b, b12, f1, nxz2);
    // ---- L4: module 2 with inline ballq2 (4-iter scan, cheap) ----
    m2bq_kernel<<<131072 / 128, 256, 0, stream>>>(
        nxz1, nxz2, f1, w20p, b20, w21b, b21, w22b, b22, f2);
    // ---- L5-L7: module 3 ----
    l30_kernel<<<dim3(4096 / 128, 2), 256, 0, stream>>>(nxz2, f2, w30p, b30, C1);
    mfma_gemm<64><<<dim3(4096 / 64, 4), 256, 0, stream>>>(C1, w31b, b31, C2, 4096, 512, 256);
    gemm_pool128<<<dim3(4096 / 128, 8), 256, 0, stream>>>(C2, w32b, b32, out);
}

// Round 8
// 441.027 us; speedup vs baseline: 1.1464x; 1.0188x over previous
//
#include <hip/hip_runtime.h>
#include <hip/hip_bf16.h>
#include <cstdint>
#include <cstddef>

// Problem constants: data (4,8,4096,3) -> 32 batches x 4096 points
#define BT 32
#define N1 4096
#define S1 256
#define S2 128
#define KNB 32

typedef __attribute__((ext_vector_type(8))) short short8;   // 8 bf16 in 4 VGPRs
typedef __attribute__((ext_vector_type(4))) float f32x4;

__device__ __forceinline__ float sqdist(float ax, float ay, float az,
                                        float bx, float by, float bz) {
    // exact replication of sum((a-b)**2, axis=-1): mul then left-to-right add, NO fma
    float dx = __fsub_rn(ax, bx), dy = __fsub_rn(ay, by), dz = __fsub_rn(az, bz);
    return __fadd_rn(__fadd_rn(__fmul_rn(dx, dx), __fmul_rn(dy, dy)), __fmul_rn(dz, dz));
}

// bf16 round-to-nearest-even (values here are finite)
__device__ __forceinline__ unsigned short f2bf(float f) {
    unsigned u = __float_as_uint(f);
    return (unsigned short)((u + 0x7FFFu + ((u >> 16) & 1u)) >> 16);
}
__device__ __forceinline__ float bf2f(unsigned short h) {
    return __uint_as_float(((unsigned)h) << 16);
}

// pack (value, index) for argmax-with-first-index-tie-break: distances >= 0 so float
// bits are monotonic as uint; on equal value, larger ~idx == smaller idx wins.
__device__ __forceinline__ unsigned long long packvi(float v, int idx) {
    return ((unsigned long long)__float_as_uint(v) << 32) | (unsigned)(~idx);
}

// DPP row-rotate max for u64 (rotate within 16-lane rows; commutative reduce)
template <int CTRL>
__device__ __forceinline__ unsigned long long dppmax(unsigned long long v) {
    int lo = (int)(unsigned)(v & 0xFFFFFFFFull);
    int hi = (int)(unsigned)(v >> 32);
    int lo2 = __builtin_amdgcn_update_dpp(0, lo, CTRL, 0xF, 0xF, false);
    int hi2 = __builtin_amdgcn_update_dpp(0, hi, CTRL, 0xF, 0xF, false);
    unsigned long long o = ((unsigned long long)(unsigned)hi2 << 32) | (unsigned)lo2;
    return o > v ? o : v;
}
#define ROR1 0x121
#define ROR2 0x122
#define ROR4 0x124
#define ROR8 0x128

// wave-level ball query: scans X[0..n), radius^2 r2, writes KNB indices to gl[].
// R19: the `cnt < KNB` early exit REMOVED from the loop condition — provably dead
// (found==false <=> cnt==0; all writes pos<KNB-guarded) but it made the trip count
// data-dependent, blocking compiler load pipelining (each iter serialized on the
// previous ballot). Fixed trip count -> loads software-pipeline. Results bit-identical.
// R18 LEDGER: fused long scans in low-occupancy MFMA kernels are disastrous (R17:
// +56us); standalone high-TLP launches hide the chain. Short (4-iter) scans fuse free.
__device__ __forceinline__ void ballq_wave(const float* __restrict__ X, int n,
                                           float cx, float cy, float cz, float r2,
                                           int lane, int* __restrict__ gl) {
    int cnt = 0, first = 0;
    bool found = false;
    for (int j0 = 0; j0 < n; j0 += 64) {
        int j = j0 + lane;
        float d2 = sqdist(cx, cy, cz, X[j * 3 + 0], X[j * 3 + 1], X[j * 3 + 2]);
        bool hit = d2 < r2;
        unsigned long long mask = __ballot(hit);
        if (!found && mask) { first = j0 + __builtin_ctzll(mask); found = true; }
        if (hit) {
            int pos = cnt + __popcll(mask & ((1ull << lane) - 1ull));
            if (pos < KNB) gl[pos] = j;
        }
        cnt += __popcll(mask);
    }
    if (cnt < KNB) {
        int pad = found ? first : 0;
        if (lane >= cnt && lane < KNB) gl[lane] = pad;
    }
}

// ---------------- FPS module 1 + wconv PACKED into one launch (R15, kept) -----------
// fps1: blocks 0..31 (one per batch, EXACT byte-for-byte R8/R9/R11-proven 153us code).
// wconv: blocks 32..3247 (~5us + launch gap hidden under fps1's 153us serial chain).
// FPS DO-NOT-TOUCH ledger (all measured equal or worse): 512-thr (per-CU issue-bound),
// payload-DPP reduce, coord-prefetch, single-slot LDS atomicMax (R13: +65us, DS
// serializes same-address RMW), f32x2 pk math (R14: +49us, v_pk_*_f32 has NO
// issue-rate gain on CDNA4), tree argmax (R14, part of +49us).
// fps1 per-iter critical path ~1440cyc = compute ~400 + sync chain ~1000 — structural
// for 4-wave cross-wave argmax; accepted.
//
//  w11b@0      64x64   | w12b@4096  128x64 | w20p@12288 128x192 (PERM: feat-first)
//  w21b@36864  128x128 | w22b@53248 256x128| w30p@86016 256x320 (PERM: feat-first)
//  w31b@167936 512x256 | w32b@299008 1024x512  total 823296
__global__ __launch_bounds__(256) void fps1_wconv_kernel(
    const float* __restrict__ xyz, float* __restrict__ nxz,
    const float* __restrict__ w11, const float* __restrict__ w12,
    const float* __restrict__ w20, const float* __restrict__ w21,
    const float* __restrict__ w22, const float* __restrict__ w30,
    const float* __restrict__ w31, const float* __restrict__ w32,
    unsigned short* __restrict__ wb) {
    if (blockIdx.x < 32) {
        // ================= fps1 (EXACT proven code, b = blockIdx.x) =================
        const int b = blockIdx.x, tid = threadIdx.x;
        const int lane = tid & 63, wv = tid >> 6;      // 4 waves
        const float* X = xyz + (size_t)b * (N1 * 3);
        __shared__ float4 s4[N1];                      // 64 KB
        __shared__ unsigned long long slots[2][16];
        __shared__ float hist[S1 * 3];
        float px[16], py[16], pz[16], md[16];
        int bidx[16];
#pragma unroll
        for (int j = 0; j < 16; ++j) {
            int i = tid + 256 * j;
            float x = X[i * 3 + 0], y = X[i * 3 + 1], z = X[i * 3 + 2];
            s4[i] = make_float4(x, y, z, 0.f);
            px[j] = x; py[j] = y; pz[j] = z;
            md[j] = 1e10f;
            bidx[j] = i;
        }
        if (tid == 0) { hist[0] = X[0]; hist[1] = X[1]; hist[2] = X[2]; }
        __syncthreads();
        float4 c0 = s4[0];
        float lx = c0.x, ly = c0.y, lz = c0.z;
        for (int t = 1; t < S1; ++t) {
            float bv = -1.0f; int bi = 0;
#pragma unroll
            for (int j = 0; j < 16; ++j) {
                float d = sqdist(px[j], py[j], pz[j], lx, ly, lz);
                float m = fminf(md[j], d);
                md[j] = m;
                if (m > bv) { bv = m; bi = bidx[j]; }   // ascending flat idx: first max kept
            }
            unsigned long long best = packvi(bv, bi);
            best = dppmax<ROR1>(best);
            best = dppmax<ROR2>(best);
            best = dppmax<ROR4>(best);
            best = dppmax<ROR8>(best);                  // row (16-lane) max
            if ((lane & 15) == 0) slots[t & 1][wv * 4 + (lane >> 4)] = best;
            __syncthreads();
            unsigned long long w = slots[t & 1][lane & 15];
            w = dppmax<ROR1>(w);
            w = dppmax<ROR2>(w);
            w = dppmax<ROR4>(w);
            w = dppmax<ROR8>(w);
            int vi = (int)(~(unsigned)w);
            float4 c = s4[vi];
            lx = c.x; ly = c.y; lz = c.z;
            if (tid == 0) { hist[t * 3 + 0] = lx; hist[t * 3 + 1] = ly; hist[t * 3 + 2] = lz; }
        }
        __syncthreads();
        for (int u = tid; u < S1 * 3; u += 256) nxz[(size_t)b * S1 * 3 + u] = hist[u];
    } else {
        // ================= wconv (blocks 32..3247; u covers 0..823295) ==============
        int u = (blockIdx.x - 32) * 256 + threadIdx.x;
        if (u >= 823296) return;
        const float* src; int base, Kp, Ko; int perm = 0;   // perm: feature-count, feat-first
        if      (u < 4096)   { src = w11; base = 0;      Kp = 64;  Ko = 64;  }
        else if (u < 12288)  { src = w12; base = 4096;   Kp = 64;  Ko = 64;  }
        else if (u < 36864)  { src = w20; base = 12288;  Kp = 192; Ko = 131; perm = 128; }
        else if (u < 53248)  { src = w21; base = 36864;  Kp = 128; Ko = 128; }
        else if (u < 86016)  { src = w22; base = 53248;  Kp = 128; Ko = 128; }
        else if (u < 167936) { src = w30; base = 86016;  Kp = 320; Ko = 259; perm = 256; }
        else if (u < 299008) { src = w31; base = 167936; Kp = 256; Ko = 256; }
        else                 { src = w32; base = 299008; Kp = 512; Ko = 512; }
        int local = u - base;
        int n = local / Kp, k = local - n * Kp;
        float v;
        if (perm) {
            int ksrc = (k < perm) ? (k + 3) : ((k < perm + 3) ? (k - perm) : -1);
            v = (ksrc >= 0) ? src[(size_t)n * Ko + ksrc] : 0.f;
        } else {
            v = (k < Ko) ? src[(size_t)n * Ko + k] : 0.f;
        }
        wb[u] = f2bf(v);
    }
}

// ---------------- Ball query 1 STANDALONE (R18 structure; R19 pipelined scan) --------
__global__ __launch_bounds__(256) void ballq1_kernel(const float* __restrict__ xyz,
                                                     const float* __restrict__ nxz,
                                                     int* __restrict__ gidx) {
    const int wid = (blockIdx.x * 256 + threadIdx.x) >> 6;
    const int lane = threadIdx.x & 63;
    const int b = wid >> 8;
    ballq_wave(xyz + (size_t)b * (N1 * 3), N1,
               nxz[(size_t)wid * 3 + 0], nxz[(size_t)wid * 3 + 1], nxz[(size_t)wid * 3 + 2],
               (float)(0.2 * 0.2), lane, gidx + (size_t)wid * KNB);
}

// ---------------- L3: fps2 + m1 PACKED (R16 structure, kept) -------------------------
// fps2 (blocks 0..31, first): 26us serial chain, hidden under m1.
// m1 (blocks 32..2079): gathers via g1 from the standalone ballq1 launch.
__global__ __launch_bounds__(256) void m1_fps2_kernel(
    const float* __restrict__ xyz, const float* __restrict__ nxz,
    const int* __restrict__ g1,
    const float* __restrict__ w10, const float* __restrict__ b10,
    const unsigned short* __restrict__ w11b, const float* __restrict__ b11,
    const unsigned short* __restrict__ w12b, const float* __restrict__ b12,
    unsigned short* __restrict__ f1,
    float* __restrict__ nxz2) {
    if (blockIdx.x < 32) {
        // ================= fps2 (one wave per batch; threads 64..255 exit) ==========
        if (threadIdx.x >= 64) return;
        const int b = blockIdx.x, lane = threadIdx.x;
        const float* X = nxz + (size_t)b * (S1 * 3);
        __shared__ float4 s4f[S1];
        float px[4], py[4], pz[4], md[4];
        int bidx[4];
#pragma unroll
        for (int j = 0; j < 4; ++j) {
            int i = lane + 64 * j;
            float x = X[i * 3 + 0], y = X[i * 3 + 1], z = X[i * 3 + 2];
            s4f[i] = make_float4(x, y, z, 0.f);
            px[j] = x; py[j] = y; pz[j] = z;
            md[j] = 1e10f;
            bidx[j] = i;
        }
        if (lane == 0) {
            nxz2[(size_t)b * S2 * 3 + 0] = X[0];
            nxz2[(size_t)b * S2 * 3 + 1] = X[1];
            nxz2[(size_t)b * S2 * 3 + 2] = X[2];
        }
        // single wave: LDS writes above are wave-synchronous
        float4 cc = s4f[0];
        float lx = cc.x, ly = cc.y, lz = cc.z;
        for (int t = 1; t < S2; ++t) {
            float bv = -1.0f; int bi = 0;
#pragma unroll
            for (int j = 0; j < 4; ++j) {
                float d = sqdist(px[j], py[j], pz[j], lx, ly, lz);
                float m = fminf(md[j], d);
                md[j] = m;
                if (m > bv) { bv = m; bi = bidx[j]; }
            }
            unsigned long long best = packvi(bv, bi);
            best = dppmax<ROR1>(best);
            best = dppmax<ROR2>(best);
            best = dppmax<ROR4>(best);
            best = dppmax<ROR8>(best);
            { unsigned long long o = __shfl_xor(best, 16); best = o > best ? o : best; }
            { unsigned long long o = __shfl_xor(best, 32); best = o > best ? o : best; }
            int vi = (int)(~(unsigned)best);
            float4 c = s4f[vi];
            lx = c.x; ly = c.y; lz = c.z;
            if (lane == 0) {
                float* dst = nxz2 + ((size_t)b * S2 + t) * 3;
                dst[0] = lx; dst[1] = ly; dst[2] = lz;
            }
        }
        return;
    }
    // ================= m1 (blocks 32..2079) =========================================
    constexpr int AP = 72;
    __shared__ __align__(16) unsigned short As[128 * AP];
    __shared__ __align__(16) unsigned short Hs[128 * AP];
    __shared__ __align__(16) unsigned short Bs[192 * AP];   // w11 (64 rows) + w12 (128 rows)
    __shared__ float sxyz[128 * 3];
    const int t = threadIdx.x;
    const int lane = t & 63, w = t >> 6;
    const int r16 = lane & 15, q = lane >> 4;
    const int m0 = (blockIdx.x - 32) * 128;

    if (t < 128) {
        int row = m0 + t, bs = row >> 5, b = bs >> 8, j = g1[row];
        const float* P = xyz + ((size_t)b * N1 + j) * 3;
        const float* Cc = nxz + (size_t)bs * 3;
        sxyz[t * 3 + 0] = P[0] - Cc[0];
        sxyz[t * 3 + 1] = P[1] - Cc[1];
        sxyz[t * 3 + 2] = P[2] - Cc[2];
    }
    // stage w11 (rows 0..63) and w12 (rows 64..191) in one pass
    for (int c = t; c < 192 * 8; c += 256) {
        int row = c >> 3, ch = c & 7;
        const unsigned short* src = (row < 64) ? &w11b[row * 64 + ch * 8]
                                               : &w12b[(row - 64) * 64 + ch * 8];
        *(short8*)&Bs[row * AP + ch * 8] = *(const short8*)src;
    }
    __syncthreads();
    {
        const int r = t >> 1, half = (t & 1) * 32;
        const float x = sxyz[r * 3 + 0], y = sxyz[r * 3 + 1], z = sxyz[r * 3 + 2];
        unsigned short tmp[32];
#pragma unroll
        for (int o = 0; o < 32; ++o) {
            int oo = half + o;
            float acc = b10[oo];
            acc = fmaf(x, w10[oo * 3 + 0], acc);
            acc = fmaf(y, w10[oo * 3 + 1], acc);
            acc = fmaf(z, w10[oo * 3 + 2], acc);
            tmp[o] = f2bf(fmaxf(acc, 0.f));
        }
#pragma unroll
        for (int c2 = 0; c2 < 4; ++c2)
            *(short8*)&As[r * AP + half + c2 * 8] = *(short8*)&tmp[c2 * 8];
    }
    __syncthreads();
    {
        f32x4 acc[2][4];
#pragma unroll
        for (int i = 0; i < 2; ++i)
#pragma unroll
            for (int j = 0; j < 4; ++j) acc[i][j] = (f32x4){0.f, 0.f, 0.f, 0.f};
#pragma unroll
        for (int kk = 0; kk < 64; kk += 32) {
            short8 a0 = *(const short8*)&As[(w * 32 + r16) * AP + kk + q * 8];
            short8 a1 = *(const short8*)&As[(w * 32 + 16 + r16) * AP + kk + q * 8];
#pragma unroll
            for (int j = 0; j < 4; ++j) {
                short8 bf = *(const short8*)&Bs[(j * 16 + r16) * AP + kk + q * 8];
                acc[0][j] = __builtin_amdgcn_mfma_f32_16x16x32_bf16(a0, bf, acc[0][j], 0, 0, 0);
                acc[1][j] = __builtin_amdgcn_mfma_f32_16x16x32_bf16(a1, bf, acc[1][j], 0, 0, 0);
            }
        }
#pragma unroll
        for (int i = 0; i < 2; ++i)
#pragma unroll
            for (int j = 0; j < 4; ++j) {
                int col = j * 16 + r16;
                float bv = b11[col];
#pragma unroll
                for (int r = 0; r < 4; ++r) {
                    int row = w * 32 + i * 16 + q * 4 + r;
                    Hs[row * AP + col] = f2bf(fmaxf(acc[i][j][r] + bv, 0.f));
                }
            }
    }
    __syncthreads();   // Hs fully written; Bs rows 64.. already hold w12
    {
        f32x4 acc[2][8];
#pragma unroll
        for (int i = 0; i < 2; ++i)
#pragma unroll
            for (int j = 0; j < 8; ++j) acc[i][j] = (f32x4){0.f, 0.f, 0.f, 0.f};
#pragma unroll
        for (int kk = 0; kk < 64; kk += 32) {
            short8 a0 = *(const short8*)&Hs[(w * 32 + r16) * AP + kk + q * 8];
            short8 a1 = *(const short8*)&Hs[(w * 32 + 16 + r16) * AP + kk + q * 8];
#pragma unroll
            for (int j = 0; j < 8; ++j) {
                short8 bf = *(const short8*)&Bs[(64 + j * 16 + r16) * AP + kk + q * 8];
                acc[0][j] = __builtin_amdgcn_mfma_f32_16x16x32_bf16(a0, bf, acc[0][j], 0, 0, 0);
                acc[1][j] = __builtin_amdgcn_mfma_f32_16x16x32_bf16(a1, bf, acc[1][j], 0, 0, 0);
            }
        }
#pragma unroll
        for (int j = 0; j < 8; ++j) {
            int col = j * 16 + r16;
            float bv = b12[col];
            float mv = 0.f;
#pragma unroll
            for (int i = 0; i < 2; ++i)
#pragma unroll
                for (int r = 0; r < 4; ++r)
                    mv = fmaxf(mv, acc[i][j][r] + bv);
            mv = fmaxf(mv, __shfl_xor(mv, 16));
            mv = fmaxf(mv, __shfl_xor(mv, 32));
            if (q == 0)
                f1[(size_t)((m0 >> 5) + w) * 128 + col] = f2bf(mv);
        }
    }
}

// ---------------- L4: Module 2 fused + INLINE ballq2 (R17 m2bq; R19 x3 epilogue) -----
// ballq2's scan is only 4 fixed-trip iterations over S1=256 L2-hot points — cheap.
// R19: output written in CONCAT layout x3[4096][320] (cols 0..255 = features,
// 256..258 = bf16(xyz), 259..319 = explicit 0) so module-3 L0 becomes a plain
// mfma_gemm<64> with K=320 against the already-feat-first w30p — the bespoke
// l30_kernel (64-block grid) is deleted. Zeros are REQUIRED: uninit bf16 could be
// NaN and NaN*0 != 0 in the MFMA.
__global__ __launch_bounds__(256) void m2bq_kernel(
    const float* __restrict__ xyz1, const float* __restrict__ nxz2,
    const unsigned short* __restrict__ f1,
    const unsigned short* __restrict__ w20p, const float* __restrict__ b20,
    const unsigned short* __restrict__ w21b, const float* __restrict__ b21,
    const unsigned short* __restrict__ w22b, const float* __restrict__ b22,
    unsigned short* __restrict__ x3) {
    constexpr int AP = 72, HP = 136;
    __shared__ __align__(16) unsigned short smem[36864];   // 72 KB
    unsigned short* R1 = smem;
    unsigned short* R2 = smem + 18432;
    unsigned short* As = R1;
    unsigned short* Bs = R1 + 9216;
    unsigned short* W21 = R1;            // full w21, stride HP (17408 shorts)
    unsigned short* H1 = R2;
    unsigned short* H2 = R1;
    unsigned short* Bs2 = R2;
    __shared__ int ribase[128];
    __shared__ unsigned short sxb[128 * 3];
    __shared__ int gl2[4][KNB];
    const int t = threadIdx.x;
    const int lane = t & 63, w = t >> 6;
    const int r16 = lane & 15, q = lane >> 4;
    const int m0 = blockIdx.x * 128;

    // ---- inline ballq2: wave w computes center (m0>>5)+w's 32-neighbor list ----
    {
        const int cs = (m0 >> 5) + w;          // global center id [0,4096)
        const int bb = cs >> 7;
        const float* Cc = nxz2 + (size_t)cs * 3;
        ballq_wave(xyz1 + (size_t)bb * (S1 * 3), S1,
                   Cc[0], Cc[1], Cc[2], (float)(0.4 * 0.4), lane, gl2[w]);
    }
    __syncthreads();                            // gl2 ready for cross-wave gather
    if (t < 128) {
        int row = m0 + t, bs = row >> 5, b = bs >> 7, j = gl2[t >> 5][t & 31];
        ribase[t] = (b * 256 + j) * 128;
        const float* P = xyz1 + ((size_t)b * S1 + j) * 3;
        const float* Cc = nxz2 + (size_t)bs * 3;
        sxb[t * 3 + 0] = f2bf(P[0] - Cc[0]);
        sxb[t * 3 + 1] = f2bf(P[1] - Cc[1]);
        sxb[t * 3 + 2] = f2bf(P[2] - Cc[2]);
    }
    __syncthreads();

    // ---- L0: K=192 (3 tiles), N=128 ----
    f32x4 acc[2][8];
#pragma unroll
    for (int i = 0; i < 2; ++i)
#pragma unroll
        for (int j = 0; j < 8; ++j) acc[i][j] = (f32x4){0.f, 0.f, 0.f, 0.f};
    for (int kt = 0; kt < 3; ++kt) {
        const int k0 = kt * 64;
        if (kt < 2) {
            for (int c = t; c < 128 * 8; c += 256) {
                int row = c >> 3, ch = c & 7;
                *(short8*)&As[row * AP + ch * 8] =
                    *(const short8*)&f1[(size_t)ribase[row] + k0 + ch * 8];
            }
        } else {
            for (int c = t; c < 128 * 8; c += 256) {
                int row = c >> 3, ch = c & 7;
                short8 v = (short8){0, 0, 0, 0, 0, 0, 0, 0};
                if (ch == 0) {
                    v[0] = (short)sxb[row * 3 + 0];
                    v[1] = (short)sxb[row * 3 + 1];
                    v[2] = (short)sxb[row * 3 + 2];
                }
                *(short8*)&As[row * AP + ch * 8] = v;
            }
        }
        for (int c = t; c < 128 * 8; c += 256) {
            int row = c >> 3, ch = c & 7;
            *(short8*)&Bs[row * AP + ch * 8] =
                *(const short8*)&w20p[(size_t)row * 192 + k0 + ch * 8];
        }
        __syncthreads();
#pragma unroll
        for (int kk = 0; kk < 64; kk += 32) {
            short8 a0 = *(const short8*)&As[(w * 32 + r16) * AP + kk + q * 8];
            short8 a1 = *(const short8*)&As[(w * 32 + 16 + r16) * AP + kk + q * 8];
#pragma unroll
            for (int j = 0; j < 8; ++j) {
                short8 bf = *(const short8*)&Bs[(j * 16 + r16) * AP + kk + q * 8];
                acc[0][j] = __builtin_amdgcn_mfma_f32_16x16x32_bf16(a0, bf, acc[0][j], 0, 0, 0);
                acc[1][j] = __builtin_amdgcn_mfma_f32_16x16x32_bf16(a1, bf, acc[1][j], 0, 0, 0);
            }
        }
        __syncthreads();
    }
#pragma unroll
    for (int i = 0; i < 2; ++i)
#pragma unroll
        for (int j = 0; j < 8; ++j) {
            int col = j * 16 + r16;
            float bv = b20[col];
#pragma unroll
            for (int r = 0; r < 4; ++r) {
                int row = w * 32 + i * 16 + q * 4 + r;
                H1[row * HP + col] = f2bf(fmaxf(acc[i][j][r] + bv, 0.f));
            }
        }
    // ---- L1: K=128, N=128; stage FULL w21 into R1 (As/Bs dead), single barrier ----
    __syncthreads();
    for (int c = t; c < 128 * 16; c += 256) {
        int row = c >> 4, ch = c & 15;
        *(short8*)&W21[row * HP + ch * 8] =
            *(const short8*)&w21b[(size_t)row * 128 + ch * 8];
    }
    __syncthreads();
#pragma unroll
    for (int i = 0; i < 2; ++i)
#pragma unroll
        for (int j = 0; j < 8; ++j) acc[i][j] = (f32x4){0.f, 0.f, 0.f, 0.f};
#pragma unroll
    for (int kk = 0; kk < 128; kk += 32) {
        short8 a0 = *(const short8*)&H1[(w * 32 + r16) * HP + kk + q * 8];
        short8 a1 = *(const short8*)&H1[(w * 32 + 16 + r16) * HP + kk + q * 8];
#pragma unroll
        for (int j = 0; j < 8; ++j) {
            short8 bf = *(const short8*)&W21[(j * 16 + r16) * HP + kk + q * 8];
            acc[0][j] = __builtin_amdgcn_mfma_f32_16x16x32_bf16(a0, bf, acc[0][j], 0, 0, 0);
            acc[1][j] = __builtin_amdgcn_mfma_f32_16x16x32_bf16(a1, bf, acc[1][j], 0, 0, 0);
        }
    }
    __syncthreads();   // all waves done reading W21 (R1); H2 overwrites R1
#pragma unroll
    for (int i = 0; i < 2; ++i)
#pragma unroll
        for (int j = 0; j < 8; ++j) {
            int col = j * 16 + r16;
            float bv = b21[col];
#pragma unroll
            for (int r = 0; r < 4; ++r) {
                int row = w * 32 + i * 16 + q * 4 + r;
                H2[row * HP + col] = f2bf(fmaxf(acc[i][j][r] + bv, 0.f));
            }
        }
    __syncthreads();

    // ---- L2: K=128 (2 tiles), N=256 + pool ----
    f32x4 acc2[2][16];
#pragma unroll
    for (int i = 0; i < 2; ++i)
#pragma unroll
        for (int j = 0; j < 16; ++j) acc2[i][j] = (f32x4){0.f, 0.f, 0.f, 0.f};
    for (int kt = 0; kt < 2; ++kt) {
        const int k0 = kt * 64;
        for (int c = t; c < 256 * 8; c += 256) {
            int row = c >> 3, ch = c & 7;
            *(short8*)&Bs2[row * AP + ch * 8] =
                *(const short8*)&w22b[(size_t)row * 128 + k0 + ch * 8];
        }
        __syncthreads();
#pragma unroll
        for (int kk = 0; kk < 64; kk += 32) {
            short8 a0 = *(const short8*)&H2[(w * 32 + r16) * HP + k0 + kk + q * 8];
            short8 a1 = *(const short8*)&H2[(w * 32 + 16 + r16) * HP + k0 + kk + q * 8];
#pragma unroll
            for (int j = 0; j < 16; ++j) {
                short8 bf = *(const short8*)&Bs2[(j * 16 + r16) * AP + kk + q * 8];
                acc2[0][j] = __builtin_amdgcn_mfma_f32_16x16x32_bf16(a0, bf, acc2[0][j], 0, 0, 0);
                acc2[1][j] = __builtin_amdgcn_mfma_f32_16x16x32_bf16(a1, bf, acc2[1][j], 0, 0, 0);
            }
        }
        __syncthreads();
    }
    {
        const int cs = (m0 >> 5) + w;          // this wave's X3 row (center id)
#pragma unroll
        for (int j = 0; j < 16; ++j) {
            int col = j * 16 + r16;
            float bv = b22[col];
            float mv = 0.f;
#pragma unroll
            for (int i = 0; i < 2; ++i)
#pragma unroll
                for (int r = 0; r < 4; ++r)
                    mv = fmaxf(mv, acc2[i][j][r] + bv);
            mv = fmaxf(mv, __shfl_xor(mv, 16));
            mv = fmaxf(mv, __shfl_xor(mv, 32));
            if (q == 0)
                x3[(size_t)cs * 320 + col] = f2bf(mv);
        }
        // concat tail: cols 256..258 = bf16(xyz of this center), 259..319 = 0
        if (lane < 32) {
            int col = 256 + lane * 2;
            unsigned short v0 = 0, v1 = 0;
            if (lane == 0) {
                v0 = f2bf(nxz2[(size_t)cs * 3 + 0]);
                v1 = f2bf(nxz2[(size_t)cs * 3 + 1]);
            } else if (lane == 1) {
                v0 = f2bf(nxz2[(size_t)cs * 3 + 2]);
            }
            x3[(size_t)cs * 320 + col] = v0;
            x3[(size_t)cs * 320 + col + 1] = v1;
        }
    }
}

// ---------------- bf16 MFMA GEMM (BM templated): C = relu(X*W^T + bias), BN=128 --------
// R19: also serves module-3 L0 (X = x3 concat buffer, K=320, W = w30p feat-first).
template <int BM_>
__global__ __launch_bounds__(256) void mfma_gemm(const unsigned short* __restrict__ X,
                                                 const unsigned short* __restrict__ W,
                                                 const float* __restrict__ bias,
                                                 unsigned short* __restrict__ C,
                                                 int M, int N, int K) {
    constexpr int BK = 64, AP = BK + 8;
    constexpr int RW = BM_ / 64;         // M-frags per wave
    constexpr int WR = BM_ / 4;          // rows per wave
    __shared__ __align__(16) unsigned short As[BM_ * AP];
    __shared__ __align__(16) unsigned short Bs[128 * AP];
    const int t = threadIdx.x;
    const int lane = t & 63, w = t >> 6;
    const int m0 = blockIdx.x * BM_;
    const int n0 = blockIdx.y * 128;
    const int r16 = lane & 15, q = lane >> 4;

    f32x4 acc[RW][8];
#pragma unroll
    for (int i = 0; i < RW; ++i)
#pragma unroll
        for (int j = 0; j < 8; ++j) acc[i][j] = (f32x4){0.f, 0.f, 0.f, 0.f};

    for (int k0 = 0; k0 < K; k0 += BK) {
        for (int c = t; c < BM_ * 8; c += 256) {
            int row = c >> 3, ch = c & 7;
            *(short8*)&As[row * AP + ch * 8] =
                *(const short8*)&X[(size_t)(m0 + row) * K + k0 + ch * 8];
        }
        for (int c = t; c < 128 * 8; c += 256) {
            int row = c >> 3, ch = c & 7;
            *(short8*)&Bs[row * AP + ch * 8] =
                *(const short8*)&W[(size_t)(n0 + row) * K + k0 + ch * 8];
        }
        __syncthreads();
#pragma unroll
        for (int kk = 0; kk < BK; kk += 32) {
            short8 a[RW];
#pragma unroll
            for (int i = 0; i < RW; ++i)
                a[i] = *(const short8*)&As[(w * WR + i * 16 + r16) * AP + kk + q * 8];
#pragma unroll
            for (int j = 0; j < 8; ++j) {
                short8 bf = *(const short8*)&Bs[(j * 16 + r16) * AP + kk + q * 8];
#pragma unroll
                for (int i = 0; i < RW; ++i)
                    acc[i][j] = __builtin_amdgcn_mfma_f32_16x16x32_bf16(a[i], bf, acc[i][j], 0, 0, 0);
            }
        }
        __syncthreads();
    }
#pragma unroll
    for (int i = 0; i < RW; ++i)
#pragma unroll
        for (int j = 0; j < 8; ++j) {
            int col = n0 + j * 16 + r16;
            float bv = bias[col];
#pragma unroll
            for (int r = 0; r < 4; ++r) {
                int row = m0 + w * WR + i * 16 + q * 4 + r;
                C[(size_t)row * N + col] = f2bf(fmaxf(acc[i][j][r] + bv, 0.f));
            }
        }
}

// ---------------- Final GEMM (N=1024, K=512) + max over 128 rows -> fp32 out ----------
__global__ __launch_bounds__(256) void gemm_pool128(const unsigned short* __restrict__ X,
                                                    const unsigned short* __restrict__ W,
                                                    const float* __restrict__ bias,
                                                    float* __restrict__ out) {
    constexpr int BK = 64, AP = BK + 8, K = 512;
    __shared__ __align__(16) unsigned short As[128 * AP];
    __shared__ __align__(16) unsigned short Bs[128 * AP];
    __shared__ float pool[4][128];
    const int t = threadIdx.x;
    const int lane = t & 63, w = t >> 6;
    const int m0 = blockIdx.x * 128;
    const int n0 = blockIdx.y * 128;
    const int r16 = lane & 15, q = lane >> 4;

    f32x4 acc[2][8];
#pragma unroll
    for (int i = 0; i < 2; ++i)
#pragma unroll
        for (int j = 0; j < 8; ++j) acc[i][j] = (f32x4){0.f, 0.f, 0.f, 0.f};

    for (int k0 = 0; k0 < K; k0 += BK) {
        for (int c = t; c < 128 * 8; c += 256) {
            int row = c >> 3, ch = c & 7;
            *(short8*)&As[row * AP + ch * 8] =
                *(const short8*)&X[(size_t)(m0 + row) * K + k0 + ch * 8];
        }
        for (int c = t; c < 128 * 8; c += 256) {
            int row = c >> 3, ch = c & 7;
            *(short8*)&Bs[row * AP + ch * 8] =
                *(const short8*)&W[(size_t)(n0 + row) * K + k0 + ch * 8];
        }
        __syncthreads();
#pragma unroll
        for (int kk = 0; kk < BK; kk += 32) {
            short8 a0 = *(const short8*)&As[(w * 32 + r16) * AP + kk + q * 8];
            short8 a1 = *(const short8*)&As[(w * 32 + 16 + r16) * AP + kk + q * 8];
#pragma unroll
            for (int j = 0; j < 8; ++j) {
                short8 bf = *(const short8*)&Bs[(j * 16 + r16) * AP + kk + q * 8];
                acc[0][j] = __builtin_amdgcn_mfma_f32_16x16x32_bf16(a0, bf, acc[0][j], 0, 0, 0);
                acc[1][j] = __builtin_amdgcn_mfma_f32_16x16x32_bf16(a1, bf, acc[1][j], 0, 0, 0);
            }
        }
        __syncthreads();
    }
    // wave-level pool over its 32 rows (relu via 0-init), then cross-wave via LDS
#pragma unroll
    for (int j = 0; j < 8; ++j) {
        float bv = bias[n0 + j * 16 + r16];
        float mv = 0.f;
#pragma unroll
        for (int i = 0; i < 2; ++i)
#pragma unroll
            for (int r = 0; r < 4; ++r)
                mv = fmaxf(mv, acc[i][j][r] + bv);
        mv = fmaxf(mv, __shfl_xor(mv, 16));
        mv = fmaxf(mv, __shfl_xor(mv, 32));
        if (q == 0) pool[w][j * 16 + r16] = mv;
    }
    __syncthreads();
    if (t < 128) {
        float m = fmaxf(fmaxf(pool[0][t], pool[1][t]), fmaxf(pool[2][t], pool[3][t]));
        out[(size_t)blockIdx.x * 1024 + n0 + t] = m;
    }
}

extern "C" void kernel_launch(void* const* d_in, const int* in_sizes, int n_in,
                              void* d_out, int out_size, void* d_ws, size_t ws_size,
                              hipStream_t stream) {
    const float* data = (const float*)d_in[0];
    const float* w10 = (const float*)d_in[1];  const float* b10 = (const float*)d_in[2];
    const float* w11 = (const float*)d_in[3];  const float* b11 = (const float*)d_in[4];
    const float* w12 = (const float*)d_in[5];  const float* b12 = (const float*)d_in[6];
    const float* w20 = (const float*)d_in[7];  const float* b20 = (const float*)d_in[8];
    const float* w21 = (const float*)d_in[9];  const float* b21 = (const float*)d_in[10];
    const float* w22 = (const float*)d_in[11]; const float* b22 = (const float*)d_in[12];
    const float* w30 = (const float*)d_in[13]; const float* b30 = (const float*)d_in[14];
    const float* w31 = (const float*)d_in[15]; const float* b31 = (const float*)d_in[16];
    const float* w32 = (const float*)d_in[17]; const float* b32 = (const float*)d_in[18];
    float* out = (float*)d_out;

    char* ws = (char*)d_ws;
    size_t off = 0;
    auto alloc = [&](size_t bytes) -> void* {
        void* p = ws + off;
        off += (bytes + 255) & ~(size_t)255;
        return p;
    };
    float* nxz1 = (float*)alloc((size_t)BT * S1 * 3 * 4);
    int*   g1   = (int*)  alloc((size_t)BT * S1 * KNB * 4);
    float* nxz2 = (float*)alloc((size_t)BT * S2 * 3 * 4);
    unsigned short* wb  = (unsigned short*)alloc((size_t)823296 * 2);
    unsigned short* f1  = (unsigned short*)alloc((size_t)8192 * 128 * 2);
    unsigned short* x3  = (unsigned short*)alloc((size_t)4096 * 320 * 2);
    unsigned short* C1  = (unsigned short*)alloc((size_t)4096 * 256 * 2);
    unsigned short* C2  = (unsigned short*)alloc((size_t)4096 * 512 * 2);

    const unsigned short* w11b = wb + 0;
    const unsigned short* w12b = wb + 4096;
    const unsigned short* w20p = wb + 12288;
    const unsigned short* w21b = wb + 36864;
    const unsigned short* w22b = wb + 53248;
    const unsigned short* w30p = wb + 86016;
    const unsigned short* w31b = wb + 167936;
    const unsigned short* w32b = wb + 299008;

    // ---- L1: fps1 (blocks 0-31) + wconv (blocks 32-3247) ----
    fps1_wconv_kernel<<<32 + 3216, 256, 0, stream>>>(
        data, nxz1, w11, w12, w20, w21, w22, w30, w31, w32, wb);
    // ---- L2: ballq1 standalone (fixed-trip scan, loads pipeline) ----
    ballq1_kernel<<<(BT * S1) / 4, 256, 0, stream>>>(data, nxz1, g1);
    // ---- L3: fps2 (blocks 0-31, first) + m1 (blocks 32-2079) ----
    m1_fps2_kernel<<<32 + 2048, 256, 0, stream>>>(
        data, nxz1, g1, w10, b10, w11b, b11, w12b, b12, f1, nxz2);
    // ---- L4: module 2 with inline ballq2; writes concat buffer x3 [4096][320] ----
    m2bq_kernel<<<131072 / 128, 256, 0, stream>>>(
        nxz1, nxz2, f1, w20p, b20, w21b, b21, w22b, b22, x3);
    // ---- L5-L7: module 3 (L0 now the generic GEMM template, 128 blocks) ----
    mfma_gemm<64><<<dim3(4096 / 64, 2), 256, 0, stream>>>(x3, w30p, b30, C1, 4096, 256, 320);
    mfma_gemm<64><<<dim3(4096 / 64, 4), 256, 0, stream>>>(C1, w31b, b31, C2, 4096, 512, 256);
    gemm_pool128<<<dim3(4096 / 128, 8), 256, 0, stream>>>(C2, w32b, b32, out);
}